// Round 1
// baseline (728.992 us; speedup 1.0000x reference)
//
#include <hip/hip_runtime.h>
#include <hip/hip_bf16.h>

#define T_TOK 4096
#define HDIM  1024
#define NEXP  8
#define IDIM  1408
#define ISDIM 2816

#define BM 128
#define BN 128
#define BK 32
#define LDP 40   // padded k-stride in shorts (80 B, keeps 16 B alignment)

typedef short bf16x8 __attribute__((ext_vector_type(8)));
typedef float f32x4  __attribute__((ext_vector_type(4)));
typedef int   i32x4  __attribute__((ext_vector_type(4)));
typedef unsigned short u16x4 __attribute__((ext_vector_type(4)));

__device__ inline unsigned short f2bf(float f) {
    union { float f; unsigned u; } c; c.f = f;
    unsigned r = (c.u + 0x7FFFu + ((c.u >> 16) & 1u)) >> 16;
    return (unsigned short)r;
}

// ---------------- routing: one wave per token ----------------
__global__ __launch_bounds__(256) void route_kernel(
    const float* __restrict__ X, const float* __restrict__ GW,
    const float* __restrict__ SEG,
    int* __restrict__ topk_e, float* __restrict__ topk_w,
    float* __restrict__ sgate, int* __restrict__ counts)
{
    const int t = blockIdx.x * 4 + (threadIdx.x >> 6);
    const int lane = threadIdx.x & 63;
    float acc[NEXP];
    #pragma unroll
    for (int e = 0; e < NEXP; ++e) acc[e] = 0.f;
    float sacc = 0.f;
    const float* xr = X + (size_t)t * HDIM;
    for (int h = lane; h < HDIM; h += 64) {
        float xv = xr[h];
        f32x4 g0 = *(const f32x4*)(GW + (size_t)h * NEXP);
        f32x4 g1 = *(const f32x4*)(GW + (size_t)h * NEXP + 4);
        acc[0] += xv * g0[0]; acc[1] += xv * g0[1];
        acc[2] += xv * g0[2]; acc[3] += xv * g0[3];
        acc[4] += xv * g1[0]; acc[5] += xv * g1[1];
        acc[6] += xv * g1[2]; acc[7] += xv * g1[3];
        sacc += xv * SEG[h];
    }
    #pragma unroll
    for (int off = 32; off > 0; off >>= 1) {
        #pragma unroll
        for (int e = 0; e < NEXP; ++e) acc[e] += __shfl_down(acc[e], off);
        sacc += __shfl_down(sacc, off);
    }
    if (lane == 0) {
        int e0 = 0;
        #pragma unroll
        for (int e = 1; e < NEXP; ++e) if (acc[e] > acc[e0]) e0 = e;
        int e1 = (e0 == 0) ? 1 : 0;
        #pragma unroll
        for (int e = 0; e < NEXP; ++e)
            if (e != e0 && acc[e] > acc[e1]) e1 = e;
        float w0 = 1.f / (1.f + __expf(acc[e1] - acc[e0]));
        topk_e[t * 2]     = e0; topk_e[t * 2 + 1] = e1;
        topk_w[t * 2]     = w0; topk_w[t * 2 + 1] = 1.f - w0;
        sgate[t] = 1.f / (1.f + __expf(-sacc));
        atomicAdd(&counts[e0], 1);
        atomicAdd(&counts[e1], 1);
    }
}

__global__ void offsets_kernel(const int* __restrict__ counts,
                               int* __restrict__ seg_start,
                               int* __restrict__ cursors)
{
    if (threadIdx.x == 0) {
        int s = 0;
        for (int e = 0; e < NEXP; ++e) {
            seg_start[e] = s; cursors[e] = s; s += counts[e];
        }
    }
}

__global__ __launch_bounds__(256) void scatter_kernel(
    const int* __restrict__ topk_e, const float* __restrict__ topk_w,
    int* __restrict__ cursors, int* __restrict__ tok_ids,
    float* __restrict__ tok_w)
{
    int i = blockIdx.x * 256 + threadIdx.x;
    if (i < T_TOK * 2) {
        int e = topk_e[i];
        int pos = atomicAdd(&cursors[e], 1);
        tok_ids[pos] = i >> 1;
        tok_w[pos] = topk_w[i];
    }
}

// ---------------- fused gate+up GEMM with silu epilogue ----------------
// X: fp32 [T][Kdim] gathered rows; W row-major [Kdim][N]; Hout bf16 [rows][N]
__global__ __launch_bounds__(256) void gemm_gate_up(
    const float* __restrict__ X,
    const float* __restrict__ Wg_all, const float* __restrict__ Wu_all,
    const int* __restrict__ token_ids, const int* __restrict__ seg_start,
    const int* __restrict__ counts,
    unsigned short* __restrict__ Hout,
    int Kdim, int N, int Trows)
{
    const int e = blockIdx.z;
    int cnt, base;
    if (token_ids) { cnt = counts[e]; base = seg_start[e]; }
    else           { cnt = Trows;     base = 0; }
    const int m0 = blockIdx.y * BM;
    if (m0 >= cnt) return;
    const int n0 = blockIdx.x * BN;
    const float* Wg = Wg_all + (size_t)e * Kdim * N;
    const float* Wu = Wu_all + (size_t)e * Kdim * N;

    __shared__ unsigned short As[BM][LDP];
    __shared__ unsigned short Bgs[BN][LDP];
    __shared__ unsigned short Bus[BN][LDP];
    __shared__ int rowtok[BM];

    const int tid = threadIdx.x;
    if (tid < BM) {
        int r = m0 + tid; if (r >= cnt) r = cnt - 1;
        rowtok[tid] = token_ids ? token_ids[base + r] : r;
    }
    __syncthreads();

    f32x4 accG[4][4], accU[4][4];
    #pragma unroll
    for (int i = 0; i < 4; ++i)
        #pragma unroll
        for (int j = 0; j < 4; ++j) {
            accG[i][j] = (f32x4){0.f, 0.f, 0.f, 0.f};
            accU[i][j] = (f32x4){0.f, 0.f, 0.f, 0.f};
        }

    const int lane = tid & 63;
    const int wv = tid >> 6;
    const int wr = (wv >> 1) * 64;
    const int wc = (wv & 1) * 64;
    const int lrow = lane & 15;
    const int lkb = (lane >> 4) * 8;

    const int a_r = tid >> 3;          // 0..31
    const int a_k = (tid & 7) * 4;     // 0..28
    const int b_k = (tid >> 5) * 4;    // 0..28
    const int b_n = (tid & 31) * 4;    // 0..124

    for (int k0 = 0; k0 < Kdim; k0 += BK) {
        f32x4 av[4], vg[4], vu[4];
        #pragma unroll
        for (int rr = 0; rr < 4; ++rr) {
            int r = a_r + rr * 32;
            av[rr] = *(const f32x4*)(X + (size_t)rowtok[r] * Kdim + k0 + a_k);
        }
        #pragma unroll
        for (int j = 0; j < 4; ++j) {
            size_t off = (size_t)(k0 + b_k + j) * N + n0 + b_n;
            vg[j] = *(const f32x4*)(Wg + off);
            vu[j] = *(const f32x4*)(Wu + off);
        }
        __syncthreads();
        #pragma unroll
        for (int rr = 0; rr < 4; ++rr) {
            int r = a_r + rr * 32;
            u16x4 sv;
            #pragma unroll
            for (int j = 0; j < 4; ++j) sv[j] = f2bf(av[rr][j]);
            *(u16x4*)&As[r][a_k] = sv;
        }
        #pragma unroll
        for (int nn = 0; nn < 4; ++nn) {
            u16x4 sg, su;
            #pragma unroll
            for (int j = 0; j < 4; ++j) {
                sg[j] = f2bf(vg[j][nn]);
                su[j] = f2bf(vu[j][nn]);
            }
            *(u16x4*)&Bgs[b_n + nn][b_k] = sg;
            *(u16x4*)&Bus[b_n + nn][b_k] = su;
        }
        __syncthreads();
        bf16x8 af[4], bgf[4], buf_[4];
        #pragma unroll
        for (int m = 0; m < 4; ++m) af[m] = *(const bf16x8*)&As[wr + m * 16 + lrow][lkb];
        #pragma unroll
        for (int n = 0; n < 4; ++n) {
            bgf[n]  = *(const bf16x8*)&Bgs[wc + n * 16 + lrow][lkb];
            buf_[n] = *(const bf16x8*)&Bus[wc + n * 16 + lrow][lkb];
        }
        #pragma unroll
        for (int m = 0; m < 4; ++m)
            #pragma unroll
            for (int n = 0; n < 4; ++n) {
                accG[m][n] = __builtin_amdgcn_mfma_f32_16x16x32_bf16(af[m], bgf[n],  accG[m][n], 0, 0, 0);
                accU[m][n] = __builtin_amdgcn_mfma_f32_16x16x32_bf16(af[m], buf_[n], accU[m][n], 0, 0, 0);
            }
    }

    const int l4 = (lane >> 4) * 4;
    #pragma unroll
    for (int m = 0; m < 4; ++m)
        #pragma unroll
        for (int n = 0; n < 4; ++n)
            #pragma unroll
            for (int j = 0; j < 4; ++j) {
                int r = wr + m * 16 + l4 + j;
                if (m0 + r < cnt) {
                    int c = n0 + wc + n * 16 + lrow;
                    float g = accG[m][n][j], u = accU[m][n][j];
                    float hv = g / (1.f + __expf(-g)) * u;
                    Hout[(size_t)(base + m0 + r) * N + c] = f2bf(hv);
                }
            }
}

// ---------------- down GEMM: Hin(bf16) @ Wd, scaled add into Out ----------------
__global__ __launch_bounds__(256) void gemm_down(
    const unsigned short* __restrict__ Hin,
    const float* __restrict__ Wd_all,
    const int* __restrict__ token_ids, const int* __restrict__ seg_start,
    const int* __restrict__ counts,
    const float* __restrict__ roww_in,
    float* __restrict__ Out,
    int Kdim, int N, int Trows)
{
    const int e = blockIdx.z;
    int cnt, base;
    if (token_ids) { cnt = counts[e]; base = seg_start[e]; }
    else           { cnt = Trows;     base = 0; }
    const int m0 = blockIdx.y * BM;
    if (m0 >= cnt) return;
    const int n0 = blockIdx.x * BN;
    const float* Wd = Wd_all + (size_t)e * Kdim * N;

    __shared__ unsigned short As[BM][LDP];
    __shared__ unsigned short Bs[BN][LDP];
    __shared__ int   rowtok[BM];
    __shared__ float roww[BM];

    const int tid = threadIdx.x;
    if (tid < BM) {
        int r = m0 + tid; if (r >= cnt) r = cnt - 1;
        if (token_ids) { rowtok[tid] = token_ids[base + r]; roww[tid] = roww_in[base + r]; }
        else           { rowtok[tid] = r;                   roww[tid] = roww_in[r]; }
    }
    __syncthreads();

    f32x4 acc[4][4];
    #pragma unroll
    for (int i = 0; i < 4; ++i)
        #pragma unroll
        for (int j = 0; j < 4; ++j) acc[i][j] = (f32x4){0.f, 0.f, 0.f, 0.f};

    const int lane = tid & 63;
    const int wv = tid >> 6;
    const int wr = (wv >> 1) * 64;
    const int wc = (wv & 1) * 64;
    const int lrow = lane & 15;
    const int lkb = (lane >> 4) * 8;

    const int a_r = tid >> 2;          // 0..63
    const int a_k = (tid & 3) * 8;     // 0,8,16,24
    const int b_k = (tid >> 5) * 4;
    const int b_n = (tid & 31) * 4;

    for (int k0 = 0; k0 < Kdim; k0 += BK) {
        i32x4 av[2];
        #pragma unroll
        for (int rr = 0; rr < 2; ++rr) {
            int r = a_r + rr * 64;
            int hr = m0 + r; if (hr >= cnt) hr = cnt - 1;
            av[rr] = *(const i32x4*)(Hin + (size_t)(base + hr) * Kdim + k0 + a_k);
        }
        f32x4 vb[4];
        #pragma unroll
        for (int j = 0; j < 4; ++j)
            vb[j] = *(const f32x4*)(Wd + (size_t)(k0 + b_k + j) * N + n0 + b_n);
        __syncthreads();
        #pragma unroll
        for (int rr = 0; rr < 2; ++rr)
            *(i32x4*)&As[a_r + rr * 64][a_k] = av[rr];
        #pragma unroll
        for (int nn = 0; nn < 4; ++nn) {
            u16x4 s;
            #pragma unroll
            for (int j = 0; j < 4; ++j) s[j] = f2bf(vb[j][nn]);
            *(u16x4*)&Bs[b_n + nn][b_k] = s;
        }
        __syncthreads();
        bf16x8 af[4], bf[4];
        #pragma unroll
        for (int m = 0; m < 4; ++m) af[m] = *(const bf16x8*)&As[wr + m * 16 + lrow][lkb];
        #pragma unroll
        for (int n = 0; n < 4; ++n) bf[n] = *(const bf16x8*)&Bs[wc + n * 16 + lrow][lkb];
        #pragma unroll
        for (int m = 0; m < 4; ++m)
            #pragma unroll
            for (int n = 0; n < 4; ++n)
                acc[m][n] = __builtin_amdgcn_mfma_f32_16x16x32_bf16(af[m], bf[n], acc[m][n], 0, 0, 0);
    }

    const int l4 = (lane >> 4) * 4;
    #pragma unroll
    for (int m = 0; m < 4; ++m)
        #pragma unroll
        for (int n = 0; n < 4; ++n)
            #pragma unroll
            for (int j = 0; j < 4; ++j) {
                int r = wr + m * 16 + l4 + j;
                if (m0 + r < cnt) {
                    int c = n0 + wc + n * 16 + lrow;
                    atomicAdd(&Out[(size_t)rowtok[r] * N + c], acc[m][n][j] * roww[r]);
                }
            }
}

// ---------------- launch ----------------
extern "C" void kernel_launch(void* const* d_in, const int* in_sizes, int n_in,
                              void* d_out, int out_size, void* d_ws, size_t ws_size,
                              hipStream_t stream)
{
    const float* X   = (const float*)d_in[0];
    const float* GW  = (const float*)d_in[1];
    const float* WG  = (const float*)d_in[2];
    const float* WU  = (const float*)d_in[3];
    const float* WD  = (const float*)d_in[4];
    const float* SG  = (const float*)d_in[5];
    const float* SU  = (const float*)d_in[6];
    const float* SD  = (const float*)d_in[7];
    const float* SEG = (const float*)d_in[8];
    float* Out = (float*)d_out;

    char* ws = (char*)d_ws;
    int*   counts    = (int*)(ws + 0);
    int*   seg_start = (int*)(ws + 64);
    int*   cursors   = (int*)(ws + 128);
    int*   topk_e    = (int*)(ws + 1024);
    float* topk_w    = (float*)(ws + 1024 + 32768);
    float* sgate     = (float*)(ws + 1024 + 65536);
    int*   tok_ids   = (int*)(ws + 1024 + 65536 + 16384);
    float* tok_w     = (float*)(ws + 1024 + 65536 + 16384 + 32768);
    unsigned short* Hact = (unsigned short*)(ws + (1 << 18));       // 8192 x 1408 bf16
    unsigned short* Hs   = (unsigned short*)(ws + (size_t)32 * 1024 * 1024); // 4096 x 2816 bf16

    hipMemsetAsync(d_out, 0, (size_t)out_size * sizeof(float), stream);
    hipMemsetAsync(counts, 0, 64, stream);

    route_kernel<<<T_TOK / 4, 256, 0, stream>>>(X, GW, SEG, topk_e, topk_w, sgate, counts);
    offsets_kernel<<<1, 64, 0, stream>>>(counts, seg_start, cursors);
    scatter_kernel<<<(T_TOK * 2) / 256, 256, 0, stream>>>(topk_e, topk_w, cursors, tok_ids, tok_w);

    // expert FFNs
    gemm_gate_up<<<dim3(IDIM / BN, T_TOK / BM, NEXP), 256, 0, stream>>>(
        X, WG, WU, tok_ids, seg_start, counts, Hact, HDIM, IDIM, 0);
    gemm_down<<<dim3(HDIM / BN, T_TOK / BM, NEXP), 256, 0, stream>>>(
        Hact, WD, tok_ids, seg_start, counts, tok_w, Out, IDIM, HDIM, 0);

    // shared expert
    gemm_gate_up<<<dim3(ISDIM / BN, T_TOK / BM, 1), 256, 0, stream>>>(
        X, SG, SU, nullptr, nullptr, nullptr, Hs, HDIM, ISDIM, T_TOK);
    gemm_down<<<dim3(HDIM / BN, T_TOK / BM, 1), 256, 0, stream>>>(
        Hs, SD, nullptr, nullptr, nullptr, sgate, Out, ISDIM, HDIM, T_TOK);
}

// Round 2
// 576.606 us; speedup vs baseline: 1.2643x; 1.2643x over previous
//
#include <hip/hip_runtime.h>
#include <hip/hip_bf16.h>

#define T_TOK 4096
#define HDIM  1024
#define NEXP  8
#define IDIM  1408
#define ISDIM 2816

typedef short bf16x8 __attribute__((ext_vector_type(8)));
typedef float f32x4  __attribute__((ext_vector_type(4)));
typedef unsigned short u16;
typedef unsigned short u16x4 __attribute__((ext_vector_type(4)));
typedef unsigned short u16x8 __attribute__((ext_vector_type(8)));

typedef __attribute__((address_space(1))) const void gvoid;
typedef __attribute__((address_space(3))) void lvoid;

__device__ __forceinline__ u16 f2bf(float f) {
    union { float f; unsigned u; } c; c.f = f;
    unsigned r = (c.u + 0x7FFFu + ((c.u >> 16) & 1u)) >> 16;
    return (u16)r;
}
__device__ __forceinline__ float bf2f(u16 v) {
    union { unsigned u; float f; } c; c.u = (unsigned)v << 16; return c.f;
}
__device__ __forceinline__ void glds16(const u16* g, u16* l) {
    __builtin_amdgcn_global_load_lds((gvoid*)g, (lvoid*)l, 16, 0, 0);
}

// ---------------- routing: one wave per token ----------------
__global__ __launch_bounds__(256) void route_kernel(
    const float* __restrict__ X, const float* __restrict__ GW,
    const float* __restrict__ SEG,
    int* __restrict__ topk_e, float* __restrict__ topk_w,
    float* __restrict__ sgate, int* __restrict__ counts)
{
    const int t = blockIdx.x * 4 + (threadIdx.x >> 6);
    const int lane = threadIdx.x & 63;
    float acc[NEXP];
    #pragma unroll
    for (int e = 0; e < NEXP; ++e) acc[e] = 0.f;
    float sacc = 0.f;
    const float* xr = X + (size_t)t * HDIM;
    for (int h = lane; h < HDIM; h += 64) {
        float xv = xr[h];
        f32x4 g0 = *(const f32x4*)(GW + (size_t)h * NEXP);
        f32x4 g1 = *(const f32x4*)(GW + (size_t)h * NEXP + 4);
        acc[0] += xv * g0[0]; acc[1] += xv * g0[1];
        acc[2] += xv * g0[2]; acc[3] += xv * g0[3];
        acc[4] += xv * g1[0]; acc[5] += xv * g1[1];
        acc[6] += xv * g1[2]; acc[7] += xv * g1[3];
        sacc += xv * SEG[h];
    }
    #pragma unroll
    for (int off = 32; off > 0; off >>= 1) {
        #pragma unroll
        for (int e = 0; e < NEXP; ++e) acc[e] += __shfl_down(acc[e], off);
        sacc += __shfl_down(sacc, off);
    }
    if (lane == 0) {
        int e0 = 0;
        #pragma unroll
        for (int e = 1; e < NEXP; ++e) if (acc[e] > acc[e0]) e0 = e;
        int e1 = (e0 == 0) ? 1 : 0;
        #pragma unroll
        for (int e = 0; e < NEXP; ++e)
            if (e != e0 && acc[e] > acc[e1]) e1 = e;
        float w0 = 1.f / (1.f + __expf(acc[e1] - acc[e0]));
        topk_e[t * 2]     = e0; topk_e[t * 2 + 1] = e1;
        topk_w[t * 2]     = w0; topk_w[t * 2 + 1] = 1.f - w0;
        sgate[t] = 1.f / (1.f + __expf(-sacc));
        atomicAdd(&counts[e0], 1);
        atomicAdd(&counts[e1], 1);
    }
}

__global__ void offsets_kernel(const int* __restrict__ counts,
                               int* __restrict__ seg_start,
                               int* __restrict__ cursors)
{
    if (threadIdx.x == 0) {
        int s = 0;
        for (int e = 0; e < NEXP; ++e) {
            seg_start[e] = s; cursors[e] = s; s += counts[e];
        }
    }
}

__global__ __launch_bounds__(256) void scatter_kernel(
    const int* __restrict__ topk_e, const float* __restrict__ topk_w,
    int* __restrict__ cursors, int* __restrict__ tok_ids,
    float* __restrict__ tok_w)
{
    int i = blockIdx.x * 256 + threadIdx.x;
    if (i < T_TOK * 2) {
        int e = topk_e[i];
        int pos = atomicAdd(&cursors[e], 1);
        tok_ids[pos] = i >> 1;
        tok_w[pos] = topk_w[i];
    }
}

// ---------------- converts ----------------
__global__ __launch_bounds__(256) void cvt_x_kernel(
    const float* __restrict__ in, u16* __restrict__ out, int n)
{
    int i = (blockIdx.x * 256 + threadIdx.x) * 8;
    if (i < n) {
        f32x4 a = *(const f32x4*)(in + i);
        f32x4 b = *(const f32x4*)(in + i + 4);
        u16x8 o;
        #pragma unroll
        for (int j = 0; j < 4; ++j) { o[j] = f2bf(a[j]); o[j + 4] = f2bf(b[j]); }
        *(u16x8*)(out + i) = o;
    }
}

// in fp32 [K][N] (z-th slice from in0 if z<split else in1), out bf16 [N][K] contiguous by z
__global__ __launch_bounds__(256) void transpose_cvt(
    const float* __restrict__ in0, const float* __restrict__ in1,
    u16* __restrict__ out, int K, int N, int split)
{
    const int z = blockIdx.z;
    const float* in = (z < split) ? (in0 + (size_t)z * K * N)
                                  : (in1 + (size_t)(z - split) * K * N);
    u16* o = out + (size_t)z * N * K;

    __shared__ float tile[64][65];
    const int n0 = blockIdx.x * 64, k0 = blockIdx.y * 64;
    const int tx = threadIdx.x & 15;
    const int ty = threadIdx.x >> 4;

    #pragma unroll
    for (int p = 0; p < 4; ++p) {
        int k = ty + p * 16;
        f32x4 v = *(const f32x4*)(in + (size_t)(k0 + k) * N + n0 + tx * 4);
        *(f32x4*)&tile[k][tx * 4] = v;
    }
    __syncthreads();
    #pragma unroll
    for (int p = 0; p < 4; ++p) {
        int n = ty + p * 16;
        u16x4 w;
        #pragma unroll
        for (int j = 0; j < 4; ++j) w[j] = f2bf(tile[tx * 4 + j][n]);
        *(u16x4*)(o + (size_t)(n0 + n) * K + k0 + tx * 4) = w;
    }
}

// ---------------- standard 128x128xBK32 GEMM (m97 structure) ----------------
// A bf16 [ra][K] (rows via a_ids or direct), B bf16 [N][K] (z-th expert via b_stride)
// MODE 0: store bf16 to Outv[(base+row)*N+c]
// MODE 1: atomicAdd fp32 Outv[out_ids[base+row]*N+c] += acc*roww[base+row]
// MODE 2: store fp32 Outv[(base+row)*N+c] = acc*roww[base+row]
template<int MODE>
__global__ __launch_bounds__(256) void gemm128(
    const u16* __restrict__ A, const u16* __restrict__ B, size_t b_stride,
    void* __restrict__ Outv,
    const int* __restrict__ a_ids, const int* __restrict__ out_ids,
    const int* __restrict__ seg_start, const int* __restrict__ counts,
    const float* __restrict__ roww,
    int K, int N, int Trows)
{
    const int z = blockIdx.z;
    int cnt, base;
    if (counts) { cnt = counts[z]; base = seg_start[z]; }
    else        { cnt = Trows;     base = 0; }
    const int m0 = blockIdx.y * 128;
    if (m0 >= cnt) return;
    const int n0 = blockIdx.x * 128;
    B += (size_t)z * b_stride;

    __shared__ u16 As[128 * 32];
    __shared__ u16 Bs[128 * 32];

    const int tid = threadIdx.x;
    // staging: thread covers rows (tid>>2) and (tid>>2)+64, k-offset (tid&3)*8
    const int st_row = tid >> 2;
    const int st_k   = (tid & 3) * 8;
    int ar0 = m0 + st_row;      if (ar0 >= cnt) ar0 = cnt - 1;
    int ar1 = m0 + st_row + 64; if (ar1 >= cnt) ar1 = cnt - 1;
    const int ga0 = a_ids ? a_ids[base + ar0] : (base + ar0);
    const int ga1 = a_ids ? a_ids[base + ar1] : (base + ar1);
    const u16* a_src0 = A + (size_t)ga0 * K + st_k;
    const u16* a_src1 = A + (size_t)ga1 * K + st_k;
    const u16* b_src0 = B + (size_t)(n0 + st_row) * K + st_k;
    const u16* b_src1 = B + (size_t)(n0 + st_row + 64) * K + st_k;
    u16* as_d0 = As + tid * 8;
    u16* as_d1 = As + 2048 + tid * 8;
    u16* bs_d0 = Bs + tid * 8;
    u16* bs_d1 = Bs + 2048 + tid * 8;

    f32x4 acc[4][4];
    #pragma unroll
    for (int i = 0; i < 4; ++i)
        #pragma unroll
        for (int j = 0; j < 4; ++j) acc[i][j] = (f32x4){0.f, 0.f, 0.f, 0.f};

    const int lane = tid & 63;
    const int wv = tid >> 6;
    const int wr = (wv >> 1) * 64;
    const int wc = (wv & 1) * 64;
    const int lrow = lane & 15;
    const int lkb = (lane >> 4) * 8;

    for (int k0 = 0; k0 < K; k0 += 32) {
        glds16(a_src0 + k0, as_d0);
        glds16(a_src1 + k0, as_d1);
        glds16(b_src0 + k0, bs_d0);
        glds16(b_src1 + k0, bs_d1);
        __syncthreads();
        bf16x8 af[4], bff[4];
        #pragma unroll
        for (int m = 0; m < 4; ++m)
            af[m] = *(const bf16x8*)&As[(wr + m * 16 + lrow) * 32 + lkb];
        #pragma unroll
        for (int n = 0; n < 4; ++n)
            bff[n] = *(const bf16x8*)&Bs[(wc + n * 16 + lrow) * 32 + lkb];
        #pragma unroll
        for (int m = 0; m < 4; ++m)
            #pragma unroll
            for (int n = 0; n < 4; ++n)
                acc[m][n] = __builtin_amdgcn_mfma_f32_16x16x32_bf16(af[m], bff[n], acc[m][n], 0, 0, 0);
        __syncthreads();
    }

    const int l4 = (lane >> 4) * 4;
    #pragma unroll
    for (int m = 0; m < 4; ++m)
        #pragma unroll
        for (int n = 0; n < 4; ++n)
            #pragma unroll
            for (int j = 0; j < 4; ++j) {
                int r = wr + m * 16 + l4 + j;
                if (m0 + r < cnt) {
                    int c = n0 + wc + n * 16 + lrow;
                    if (MODE == 0) {
                        ((u16*)Outv)[(size_t)(base + m0 + r) * N + c] = f2bf(acc[m][n][j]);
                    } else if (MODE == 1) {
                        int orow = out_ids[base + m0 + r];
                        atomicAdd((float*)Outv + (size_t)orow * N + c,
                                  acc[m][n][j] * roww[base + m0 + r]);
                    } else {
                        ((float*)Outv)[(size_t)(base + m0 + r) * N + c] =
                            acc[m][n][j] * roww[base + m0 + r];
                    }
                }
            }
}

// ---------------- silu(g)*u elementwise, in-place into G ----------------
__global__ __launch_bounds__(256) void silu_mul(
    u16* __restrict__ G, const u16* __restrict__ U, int n)
{
    int i = (blockIdx.x * 256 + threadIdx.x) * 8;
    if (i < n) {
        u16x8 g = *(const u16x8*)(G + i);
        u16x8 u = *(const u16x8*)(U + i);
        u16x8 o;
        #pragma unroll
        for (int j = 0; j < 8; ++j) {
            float gf = bf2f(g[j]), uf = bf2f(u[j]);
            float hv = gf / (1.f + __expf(-gf)) * uf;
            o[j] = f2bf(hv);
        }
        *(u16x8*)(G + i) = o;
    }
}

// ---------------- launch ----------------
extern "C" void kernel_launch(void* const* d_in, const int* in_sizes, int n_in,
                              void* d_out, int out_size, void* d_ws, size_t ws_size,
                              hipStream_t stream)
{
    const float* X   = (const float*)d_in[0];
    const float* GW  = (const float*)d_in[1];
    const float* WG  = (const float*)d_in[2];
    const float* WU  = (const float*)d_in[3];
    const float* WD  = (const float*)d_in[4];
    const float* SG  = (const float*)d_in[5];
    const float* SU  = (const float*)d_in[6];
    const float* SD  = (const float*)d_in[7];
    const float* SEG = (const float*)d_in[8];
    float* Out = (float*)d_out;

    char* ws = (char*)d_ws;
    int*   counts    = (int*)(ws + 0);
    int*   seg_start = (int*)(ws + 64);
    int*   cursors   = (int*)(ws + 128);
    int*   topk_e    = (int*)(ws + 1024);
    float* topk_w    = (float*)(ws + 1024 + 32768);
    float* sgate     = (float*)(ws + 1024 + 65536);
    int*   tok_ids   = (int*)(ws + 1024 + 65536 + 16384);
    float* tok_w     = (float*)(ws + 1024 + 65536 + 16384 + 32768);

    u16* Xbf  = (u16*)(ws + 0x40000ull);            //  0.25 MB : 4096x1024 bf16 (8.4 MB)
    u16* Gbuf = (u16*)(ws + 0x900000ull);           //  9 MB    : 11.53M elems (23.1 MB)
    u16* Ubuf = (u16*)(ws + 0x2100000ull);          // 33 MB    : 11.53M elems (23.1 MB)
    u16* WGUt = (u16*)(ws + 0x3900000ull);          // 57 MB    : 16x1408x1024 (46.1 MB)
    u16* WDt  = (u16*)(ws + 0x6800000ull);          // 104 MB   : 8x1024x1408 (23.1 MB)
    u16* SGUt = (u16*)(ws + 0x8000000ull);          // 128 MB   : 2x2816x1024 (11.5 MB)
    u16* SDt  = (u16*)(ws + 0x8C00000ull);          // 140 MB   : 1024x2816 (5.8 MB)
    u16* WGt = WGUt;
    u16* WUt = WGUt + (size_t)NEXP * IDIM * HDIM;
    u16* SGt = SGUt;
    u16* SUt = SGUt + (size_t)ISDIM * HDIM;

    hipMemsetAsync(counts, 0, 64, stream);

    // routing
    route_kernel<<<T_TOK / 4, 256, 0, stream>>>(X, GW, SEG, topk_e, topk_w, sgate, counts);
    offsets_kernel<<<1, 64, 0, stream>>>(counts, seg_start, cursors);
    scatter_kernel<<<(T_TOK * 2) / 256, 256, 0, stream>>>(topk_e, topk_w, cursors, tok_ids, tok_w);

    // converts
    cvt_x_kernel<<<(T_TOK * HDIM) / (256 * 8), 256, 0, stream>>>(X, Xbf, T_TOK * HDIM);
    transpose_cvt<<<dim3(IDIM / 64, HDIM / 64, 2 * NEXP), 256, 0, stream>>>(WG, WU, WGUt, HDIM, IDIM, NEXP);
    transpose_cvt<<<dim3(HDIM / 64, IDIM / 64, NEXP), 256, 0, stream>>>(WD, WD, WDt, IDIM, HDIM, NEXP);
    transpose_cvt<<<dim3(ISDIM / 64, HDIM / 64, 2), 256, 0, stream>>>(SG, SU, SGUt, HDIM, ISDIM, 1);
    transpose_cvt<<<dim3(HDIM / 64, ISDIM / 64, 1), 256, 0, stream>>>(SD, SD, SDt, ISDIM, HDIM, 1);

    // ----- shared expert (store path, fills every element of Out) -----
    gemm128<0><<<dim3(ISDIM / 128, T_TOK / 128, 1), 256, 0, stream>>>(
        Xbf, SGt, 0, Gbuf, nullptr, nullptr, nullptr, nullptr, nullptr, HDIM, ISDIM, T_TOK);
    gemm128<0><<<dim3(ISDIM / 128, T_TOK / 128, 1), 256, 0, stream>>>(
        Xbf, SUt, 0, Ubuf, nullptr, nullptr, nullptr, nullptr, nullptr, HDIM, ISDIM, T_TOK);
    silu_mul<<<(T_TOK * ISDIM) / (256 * 8), 256, 0, stream>>>(Gbuf, Ubuf, T_TOK * ISDIM);
    gemm128<2><<<dim3(HDIM / 128, T_TOK / 128, 1), 256, 0, stream>>>(
        Gbuf, SDt, 0, Out, nullptr, nullptr, nullptr, nullptr, sgate, ISDIM, HDIM, T_TOK);

    // ----- routed experts (atomic accumulate on top) -----
    gemm128<0><<<dim3(IDIM / 128, T_TOK / 128, NEXP), 256, 0, stream>>>(
        Xbf, WGt, (size_t)IDIM * HDIM, Gbuf, tok_ids, nullptr, seg_start, counts, nullptr, HDIM, IDIM, 0);
    gemm128<0><<<dim3(IDIM / 128, T_TOK / 128, NEXP), 256, 0, stream>>>(
        Xbf, WUt, (size_t)IDIM * HDIM, Ubuf, tok_ids, nullptr, seg_start, counts, nullptr, HDIM, IDIM, 0);
    silu_mul<<<(2 * T_TOK * IDIM) / (256 * 8), 256, 0, stream>>>(Gbuf, Ubuf, 2 * T_TOK * IDIM);
    gemm128<1><<<dim3(HDIM / 128, T_TOK / 128, NEXP), 256, 0, stream>>>(
        Gbuf, WDt, (size_t)HDIM * IDIM, Out, nullptr, tok_ids, seg_start, counts, tok_w, IDIM, HDIM, 0);
}

// Round 3
// 448.562 us; speedup vs baseline: 1.6252x; 1.2855x over previous
//
#include <hip/hip_runtime.h>
#include <hip/hip_bf16.h>

#define T_TOK 4096
#define HDIM  1024
#define NEXP  8
#define IDIM  1408
#define ISDIM 2816

typedef short bf16x8 __attribute__((ext_vector_type(8)));
typedef float f32x4  __attribute__((ext_vector_type(4)));
typedef unsigned short u16;
typedef unsigned short u16x4 __attribute__((ext_vector_type(4)));
typedef unsigned short u16x8 __attribute__((ext_vector_type(8)));

typedef __attribute__((address_space(1))) const void gvoid;
typedef __attribute__((address_space(3))) void lvoid;

__device__ __forceinline__ u16 f2bf(float f) {
    union { float f; unsigned u; } c; c.f = f;
    unsigned r = (c.u + 0x7FFFu + ((c.u >> 16) & 1u)) >> 16;
    return (u16)r;
}
__device__ __forceinline__ float bf2f(u16 v) {
    union { unsigned u; float f; } c; c.u = (unsigned)v << 16; return c.f;
}
__device__ __forceinline__ void glds16(const u16* g, u16* l) {
    __builtin_amdgcn_global_load_lds((gvoid*)g, (lvoid*)l, 16, 0, 0);
}

// ---------------- routing: one wave per token (NO atomics) ----------------
__global__ __launch_bounds__(256) void route_kernel(
    const float* __restrict__ X, const float* __restrict__ GW,
    const float* __restrict__ SEG,
    int* __restrict__ topk_e, float* __restrict__ topk_w,
    float* __restrict__ sgate)
{
    const int t = blockIdx.x * 4 + (threadIdx.x >> 6);
    const int lane = threadIdx.x & 63;
    float acc[NEXP];
    #pragma unroll
    for (int e = 0; e < NEXP; ++e) acc[e] = 0.f;
    float sacc = 0.f;
    const float* xr = X + (size_t)t * HDIM;
    for (int h = lane; h < HDIM; h += 64) {
        float xv = xr[h];
        f32x4 g0 = *(const f32x4*)(GW + (size_t)h * NEXP);
        f32x4 g1 = *(const f32x4*)(GW + (size_t)h * NEXP + 4);
        acc[0] += xv * g0[0]; acc[1] += xv * g0[1];
        acc[2] += xv * g0[2]; acc[3] += xv * g0[3];
        acc[4] += xv * g1[0]; acc[5] += xv * g1[1];
        acc[6] += xv * g1[2]; acc[7] += xv * g1[3];
        sacc += xv * SEG[h];
    }
    #pragma unroll
    for (int off = 32; off > 0; off >>= 1) {
        #pragma unroll
        for (int e = 0; e < NEXP; ++e) acc[e] += __shfl_down(acc[e], off);
        sacc += __shfl_down(sacc, off);
    }
    if (lane == 0) {
        int e0 = 0;
        #pragma unroll
        for (int e = 1; e < NEXP; ++e) if (acc[e] > acc[e0]) e0 = e;
        int e1 = (e0 == 0) ? 1 : 0;
        #pragma unroll
        for (int e = 0; e < NEXP; ++e)
            if (e != e0 && acc[e] > acc[e1]) e1 = e;
        float w0 = 1.f / (1.f + __expf(acc[e1] - acc[e0]));
        topk_e[t * 2]     = e0; topk_e[t * 2 + 1] = e1;
        topk_w[t * 2]     = w0; topk_w[t * 2 + 1] = 1.f - w0;
        sgate[t] = 1.f / (1.f + __expf(-sacc));
    }
}

// ---------------- histogram: LDS-aggregated, 8 global atomics/block ----------------
__global__ __launch_bounds__(256) void hist_kernel(
    const int* __restrict__ topk_e, int* __restrict__ counts)
{
    __shared__ int h[NEXP];
    if (threadIdx.x < NEXP) h[threadIdx.x] = 0;
    __syncthreads();
    int i = blockIdx.x * 256 + threadIdx.x;
    atomicAdd(&h[topk_e[i]], 1);
    __syncthreads();
    if (threadIdx.x < NEXP) atomicAdd(&counts[threadIdx.x], h[threadIdx.x]);
}

__global__ void offsets_kernel(const int* __restrict__ counts,
                               int* __restrict__ seg_start,
                               int* __restrict__ cursors)
{
    if (threadIdx.x == 0) {
        int s = 0;
        for (int e = 0; e < NEXP; ++e) {
            seg_start[e] = s; cursors[e] = s; s += counts[e];
        }
    }
}

// ---------------- scatter: wave-ballot aggregated atomics ----------------
__global__ __launch_bounds__(256) void scatter_kernel(
    const int* __restrict__ topk_e, const float* __restrict__ topk_w,
    int* __restrict__ cursors, int* __restrict__ tok_ids,
    float* __restrict__ tok_w)
{
    const int i = blockIdx.x * 256 + threadIdx.x;
    const int lane = threadIdx.x & 63;
    const int e = topk_e[i];
    const unsigned long long lt = (1ull << lane) - 1ull;
    #pragma unroll
    for (int ex = 0; ex < NEXP; ++ex) {
        unsigned long long mask = __ballot(e == ex);
        if (mask == 0ull) continue;
        int cnt = __popcll(mask);
        int leader = __ffsll((long long)mask) - 1;
        int base_ = 0;
        if (lane == leader) base_ = atomicAdd(&cursors[ex], cnt);
        base_ = __shfl(base_, leader);
        if (e == ex) {
            int pos = base_ + __popcll(mask & lt);
            tok_ids[pos] = i >> 1;
            tok_w[pos] = topk_w[i];
        }
    }
}

// ---------------- converts ----------------
__global__ __launch_bounds__(256) void cvt_x_kernel(
    const float* __restrict__ in, u16* __restrict__ out, int n)
{
    int i = (blockIdx.x * 256 + threadIdx.x) * 8;
    if (i < n) {
        f32x4 a = *(const f32x4*)(in + i);
        f32x4 b = *(const f32x4*)(in + i + 4);
        u16x8 o;
        #pragma unroll
        for (int j = 0; j < 4; ++j) { o[j] = f2bf(a[j]); o[j + 4] = f2bf(b[j]); }
        *(u16x8*)(out + i) = o;
    }
}

// in fp32 [K][N] (z-th slice from in0 if z<split else in1), out bf16 [N][K] contiguous by z
__global__ __launch_bounds__(256) void transpose_cvt(
    const float* __restrict__ in0, const float* __restrict__ in1,
    u16* __restrict__ out, int K, int N, int split)
{
    const int z = blockIdx.z;
    const float* in = (z < split) ? (in0 + (size_t)z * K * N)
                                  : (in1 + (size_t)(z - split) * K * N);
    u16* o = out + (size_t)z * N * K;

    __shared__ float tile[64][65];
    const int n0 = blockIdx.x * 64, k0 = blockIdx.y * 64;
    const int tx = threadIdx.x & 15;
    const int ty = threadIdx.x >> 4;

    #pragma unroll
    for (int p = 0; p < 4; ++p) {
        int k = ty + p * 16;
        f32x4 v = *(const f32x4*)(in + (size_t)(k0 + k) * N + n0 + tx * 4);
        *(f32x4*)&tile[k][tx * 4] = v;
    }
    __syncthreads();
    #pragma unroll
    for (int p = 0; p < 4; ++p) {
        int n = ty + p * 16;
        u16x4 w;
        #pragma unroll
        for (int j = 0; j < 4; ++j) w[j] = f2bf(tile[tx * 4 + j][n]);
        *(u16x4*)(o + (size_t)(n0 + n) * K + k0 + tx * 4) = w;
    }
}

// ---------------- standard 128x128xBK32 GEMM (m97 structure) ----------------
// A bf16 [ra][K]; B bf16 [N][K] slice z via b_stride; z = group*nz_e + ze
// MODE 0: store bf16 to ((u16*)Outv + group*out_gstride)[(base+row)*N+c]
// MODE 1: atomicAdd fp32 Outv[out_ids[base+row]*N+c] += acc*roww[base+row]
// MODE 2: store fp32 Outv[(base+row)*N+c] = acc*roww[base+row]
template<int MODE>
__global__ __launch_bounds__(256) void gemm128(
    const u16* __restrict__ A, const u16* __restrict__ B, size_t b_stride,
    void* __restrict__ Outv, size_t out_gstride, int nz_e,
    const int* __restrict__ a_ids, const int* __restrict__ out_ids,
    const int* __restrict__ seg_start, const int* __restrict__ counts,
    const float* __restrict__ roww,
    int K, int N, int Trows)
{
    const int z = blockIdx.z;
    const int group = z / nz_e;
    const int ze = z - group * nz_e;
    int cnt, base;
    if (counts) { cnt = counts[ze]; base = seg_start[ze]; }
    else        { cnt = Trows;     base = 0; }
    const int m0 = blockIdx.y * 128;
    if (m0 >= cnt) return;
    const int n0 = blockIdx.x * 128;
    B += (size_t)z * b_stride;

    __shared__ u16 As[128 * 32];
    __shared__ u16 Bs[128 * 32];

    const int tid = threadIdx.x;
    const int st_row = tid >> 2;
    const int st_k   = (tid & 3) * 8;
    int ar0 = m0 + st_row;      if (ar0 >= cnt) ar0 = cnt - 1;
    int ar1 = m0 + st_row + 64; if (ar1 >= cnt) ar1 = cnt - 1;
    const int ga0 = a_ids ? a_ids[base + ar0] : (base + ar0);
    const int ga1 = a_ids ? a_ids[base + ar1] : (base + ar1);
    const u16* a_src0 = A + (size_t)ga0 * K + st_k;
    const u16* a_src1 = A + (size_t)ga1 * K + st_k;
    const u16* b_src0 = B + (size_t)(n0 + st_row) * K + st_k;
    const u16* b_src1 = B + (size_t)(n0 + st_row + 64) * K + st_k;
    u16* as_d0 = As + tid * 8;
    u16* as_d1 = As + 2048 + tid * 8;
    u16* bs_d0 = Bs + tid * 8;
    u16* bs_d1 = Bs + 2048 + tid * 8;

    f32x4 acc[4][4];
    #pragma unroll
    for (int i = 0; i < 4; ++i)
        #pragma unroll
        for (int j = 0; j < 4; ++j) acc[i][j] = (f32x4){0.f, 0.f, 0.f, 0.f};

    const int lane = tid & 63;
    const int wv = tid >> 6;
    const int wr = (wv >> 1) * 64;
    const int wc = (wv & 1) * 64;
    const int lrow = lane & 15;
    const int lkb = (lane >> 4) * 8;

    for (int k0 = 0; k0 < K; k0 += 32) {
        glds16(a_src0 + k0, as_d0);
        glds16(a_src1 + k0, as_d1);
        glds16(b_src0 + k0, bs_d0);
        glds16(b_src1 + k0, bs_d1);
        __syncthreads();
        bf16x8 af[4], bff[4];
        #pragma unroll
        for (int m = 0; m < 4; ++m)
            af[m] = *(const bf16x8*)&As[(wr + m * 16 + lrow) * 32 + lkb];
        #pragma unroll
        for (int n = 0; n < 4; ++n)
            bff[n] = *(const bf16x8*)&Bs[(wc + n * 16 + lrow) * 32 + lkb];
        #pragma unroll
        for (int m = 0; m < 4; ++m)
            #pragma unroll
            for (int n = 0; n < 4; ++n)
                acc[m][n] = __builtin_amdgcn_mfma_f32_16x16x32_bf16(af[m], bff[n], acc[m][n], 0, 0, 0);
        __syncthreads();
    }

    const int l4 = (lane >> 4) * 4;
    #pragma unroll
    for (int m = 0; m < 4; ++m)
        #pragma unroll
        for (int n = 0; n < 4; ++n)
            #pragma unroll
            for (int j = 0; j < 4; ++j) {
                int r = wr + m * 16 + l4 + j;
                if (m0 + r < cnt) {
                    int c = n0 + wc + n * 16 + lrow;
                    if (MODE == 0) {
                        ((u16*)Outv + group * out_gstride)[(size_t)(base + m0 + r) * N + c] = f2bf(acc[m][n][j]);
                    } else if (MODE == 1) {
                        int orow = out_ids[base + m0 + r];
                        atomicAdd((float*)Outv + (size_t)orow * N + c,
                                  acc[m][n][j] * roww[base + m0 + r]);
                    } else {
                        ((float*)Outv)[(size_t)(base + m0 + r) * N + c] =
                            acc[m][n][j] * roww[base + m0 + r];
                    }
                }
            }
}

// ---------------- silu(g)*u elementwise, in-place into G ----------------
__global__ __launch_bounds__(256) void silu_mul(
    u16* __restrict__ G, const u16* __restrict__ U, int n)
{
    int i = (blockIdx.x * 256 + threadIdx.x) * 8;
    if (i < n) {
        u16x8 g = *(const u16x8*)(G + i);
        u16x8 u = *(const u16x8*)(U + i);
        u16x8 o;
        #pragma unroll
        for (int j = 0; j < 8; ++j) {
            float gf = bf2f(g[j]), uf = bf2f(u[j]);
            float hv = gf / (1.f + __expf(-gf)) * uf;
            o[j] = f2bf(hv);
        }
        *(u16x8*)(G + i) = o;
    }
}

// ---------------- launch ----------------
extern "C" void kernel_launch(void* const* d_in, const int* in_sizes, int n_in,
                              void* d_out, int out_size, void* d_ws, size_t ws_size,
                              hipStream_t stream)
{
    const float* X   = (const float*)d_in[0];
    const float* GW  = (const float*)d_in[1];
    const float* WG  = (const float*)d_in[2];
    const float* WU  = (const float*)d_in[3];
    const float* WD  = (const float*)d_in[4];
    const float* SG  = (const float*)d_in[5];
    const float* SU  = (const float*)d_in[6];
    const float* SD  = (const float*)d_in[7];
    const float* SEG = (const float*)d_in[8];
    float* Out = (float*)d_out;

    char* ws = (char*)d_ws;
    int*   counts    = (int*)(ws + 0);
    int*   seg_start = (int*)(ws + 64);
    int*   cursors   = (int*)(ws + 128);
    int*   topk_e    = (int*)(ws + 1024);
    float* topk_w    = (float*)(ws + 1024 + 32768);
    float* sgate     = (float*)(ws + 1024 + 65536);
    int*   tok_ids   = (int*)(ws + 1024 + 65536 + 16384);
    float* tok_w     = (float*)(ws + 1024 + 65536 + 16384 + 32768);

    u16* Xbf  = (u16*)(ws + 0x40000ull);            //  4096x1024 bf16 (8.4 MB)
    u16* Gbuf = (u16*)(ws + 0x900000ull);           //  group stride 0x1800000 B
    u16* Ubuf = (u16*)(ws + 0x2100000ull);
    u16* WGUt = (u16*)(ws + 0x3900000ull);          //  16x1408x1024 (46.1 MB)
    u16* WDt  = (u16*)(ws + 0x6800000ull);          //  8x1024x1408 (23.1 MB)
    u16* SGUt = (u16*)(ws + 0x8000000ull);          //  2x2816x1024 (11.5 MB)
    u16* SDt  = (u16*)(ws + 0x8C00000ull);          //  1024x2816 (5.8 MB)
    u16* WGt = WGUt;
    u16* SGt = SGUt;
    const size_t GU_STRIDE = 0xC00000ull;           // elements (= 0x1800000 bytes)

    hipMemsetAsync(counts, 0, 64, stream);

    // routing
    route_kernel<<<T_TOK / 4, 256, 0, stream>>>(X, GW, SEG, topk_e, topk_w, sgate);
    hist_kernel<<<(T_TOK * 2) / 256, 256, 0, stream>>>(topk_e, counts);
    offsets_kernel<<<1, 64, 0, stream>>>(counts, seg_start, cursors);
    scatter_kernel<<<(T_TOK * 2) / 256, 256, 0, stream>>>(topk_e, topk_w, cursors, tok_ids, tok_w);

    // converts
    cvt_x_kernel<<<(T_TOK * HDIM) / (256 * 8), 256, 0, stream>>>(X, Xbf, T_TOK * HDIM);
    transpose_cvt<<<dim3(IDIM / 64, HDIM / 64, 2 * NEXP), 256, 0, stream>>>(WG, WU, WGUt, HDIM, IDIM, NEXP);
    transpose_cvt<<<dim3(HDIM / 64, IDIM / 64, NEXP), 256, 0, stream>>>(WD, WD, WDt, IDIM, HDIM, NEXP);
    transpose_cvt<<<dim3(ISDIM / 64, HDIM / 64, 2), 256, 0, stream>>>(SG, SU, SGUt, HDIM, ISDIM, 1);
    transpose_cvt<<<dim3(HDIM / 64, ISDIM / 64, 1), 256, 0, stream>>>(SD, SD, SDt, ISDIM, HDIM, 1);

    // ----- shared expert (store path, fills every element of Out) -----
    gemm128<0><<<dim3(ISDIM / 128, T_TOK / 128, 2), 256, 0, stream>>>(
        Xbf, SGt, (size_t)ISDIM * HDIM, Gbuf, GU_STRIDE, 1,
        nullptr, nullptr, nullptr, nullptr, nullptr, HDIM, ISDIM, T_TOK);
    silu_mul<<<(T_TOK * ISDIM) / (256 * 8), 256, 0, stream>>>(Gbuf, Ubuf, T_TOK * ISDIM);
    gemm128<2><<<dim3(HDIM / 128, T_TOK / 128, 1), 256, 0, stream>>>(
        Gbuf, SDt, 0, Out, 0, 1,
        nullptr, nullptr, nullptr, nullptr, sgate, ISDIM, HDIM, T_TOK);

    // ----- routed experts (atomic accumulate on top) -----
    gemm128<0><<<dim3(IDIM / 128, T_TOK / 128, 2 * NEXP), 256, 0, stream>>>(
        Xbf, WGt, (size_t)IDIM * HDIM, Gbuf, GU_STRIDE, NEXP,
        tok_ids, nullptr, seg_start, counts, nullptr, HDIM, IDIM, 0);
    silu_mul<<<(2 * T_TOK * IDIM) / (256 * 8), 256, 0, stream>>>(Gbuf, Ubuf, 2 * T_TOK * IDIM);
    gemm128<1><<<dim3(HDIM / 128, T_TOK / 128, NEXP), 256, 0, stream>>>(
        Gbuf, WDt, (size_t)HDIM * IDIM, Out, 0, NEXP,
        nullptr, tok_ids, seg_start, counts, tok_w, IDIM, HDIM, 0);
}

// Round 4
// 381.942 us; speedup vs baseline: 1.9086x; 1.1744x over previous
//
#include <hip/hip_runtime.h>
#include <hip/hip_bf16.h>

#define T_TOK 4096
#define HDIM  1024
#define NEXP  8
#define IDIM  1408
#define ISDIM 2816

typedef short bf16x8 __attribute__((ext_vector_type(8)));
typedef float f32x4  __attribute__((ext_vector_type(4)));
typedef unsigned short u16;
typedef unsigned short u16x4 __attribute__((ext_vector_type(4)));
typedef unsigned short u16x8 __attribute__((ext_vector_type(8)));

typedef __attribute__((address_space(1))) const void gvoid;
typedef __attribute__((address_space(3))) void lvoid;

__device__ __forceinline__ u16 f2bf(float f) {
    union { float f; unsigned u; } c; c.f = f;
    unsigned r = (c.u + 0x7FFFu + ((c.u >> 16) & 1u)) >> 16;
    return (u16)r;
}
__device__ __forceinline__ float bf2f(u16 v) {
    union { unsigned u; float f; } c; c.u = (unsigned)v << 16; return c.f;
}
__device__ __forceinline__ void glds16(const u16* g, u16* l) {
    __builtin_amdgcn_global_load_lds((gvoid*)g, (lvoid*)l, 16, 0, 0);
}

// ---------------- routing: one wave per token (no atomics) ----------------
__global__ __launch_bounds__(256) void route_kernel(
    const float* __restrict__ X, const float* __restrict__ GW,
    const float* __restrict__ SEG,
    int* __restrict__ topk_e, float* __restrict__ topk_w,
    float* __restrict__ sgate)
{
    const int t = blockIdx.x * 4 + (threadIdx.x >> 6);
    const int lane = threadIdx.x & 63;
    float acc[NEXP];
    #pragma unroll
    for (int e = 0; e < NEXP; ++e) acc[e] = 0.f;
    float sacc = 0.f;
    const float* xr = X + (size_t)t * HDIM;
    for (int h = lane; h < HDIM; h += 64) {
        float xv = xr[h];
        f32x4 g0 = *(const f32x4*)(GW + (size_t)h * NEXP);
        f32x4 g1 = *(const f32x4*)(GW + (size_t)h * NEXP + 4);
        acc[0] += xv * g0[0]; acc[1] += xv * g0[1];
        acc[2] += xv * g0[2]; acc[3] += xv * g0[3];
        acc[4] += xv * g1[0]; acc[5] += xv * g1[1];
        acc[6] += xv * g1[2]; acc[7] += xv * g1[3];
        sacc += xv * SEG[h];
    }
    #pragma unroll
    for (int off = 32; off > 0; off >>= 1) {
        #pragma unroll
        for (int e = 0; e < NEXP; ++e) acc[e] += __shfl_down(acc[e], off);
        sacc += __shfl_down(sacc, off);
    }
    if (lane == 0) {
        int e0 = 0;
        #pragma unroll
        for (int e = 1; e < NEXP; ++e) if (acc[e] > acc[e0]) e0 = e;
        int e1 = (e0 == 0) ? 1 : 0;
        #pragma unroll
        for (int e = 0; e < NEXP; ++e)
            if (e != e0 && acc[e] > acc[e1]) e1 = e;
        float w0 = 1.f / (1.f + __expf(acc[e1] - acc[e0]));
        topk_e[t * 2]     = e0; topk_e[t * 2 + 1] = e1;
        topk_w[t * 2]     = w0; topk_w[t * 2 + 1] = 1.f - w0;
        sgate[t] = 1.f / (1.f + __expf(-sacc));
    }
}

// ---------------- histogram: LDS-aggregated ----------------
__global__ __launch_bounds__(256) void hist_kernel(
    const int* __restrict__ topk_e, int* __restrict__ counts)
{
    __shared__ int h[NEXP];
    if (threadIdx.x < NEXP) h[threadIdx.x] = 0;
    __syncthreads();
    int i = blockIdx.x * 256 + threadIdx.x;
    atomicAdd(&h[topk_e[i]], 1);
    __syncthreads();
    if (threadIdx.x < NEXP) atomicAdd(&counts[threadIdx.x], h[threadIdx.x]);
}

__global__ void offsets_kernel(const int* __restrict__ counts,
                               int* __restrict__ seg_start,
                               int* __restrict__ cursors)
{
    if (threadIdx.x == 0) {
        int s = 0;
        for (int e = 0; e < NEXP; ++e) {
            seg_start[e] = s; cursors[e] = s; s += counts[e];
        }
    }
}

// ---------------- scatter: wave-ballot aggregated atomics + slot inverse map ----------------
__global__ __launch_bounds__(256) void scatter_kernel(
    const int* __restrict__ topk_e,
    int* __restrict__ cursors, int* __restrict__ tok_ids,
    int* __restrict__ slot)
{
    const int i = blockIdx.x * 256 + threadIdx.x;
    const int lane = threadIdx.x & 63;
    const int e = topk_e[i];
    const unsigned long long lt = (1ull << lane) - 1ull;
    #pragma unroll
    for (int ex = 0; ex < NEXP; ++ex) {
        unsigned long long mask = __ballot(e == ex);
        if (mask == 0ull) continue;
        int cnt = __popcll(mask);
        int leader = __ffsll((long long)mask) - 1;
        int base_ = 0;
        if (lane == leader) base_ = atomicAdd(&cursors[ex], cnt);
        base_ = __shfl(base_, leader);
        if (e == ex) {
            int pos = base_ + __popcll(mask & lt);
            tok_ids[pos] = i >> 1;
            slot[i] = pos;
        }
    }
}

// ---------------- converts ----------------
__global__ __launch_bounds__(256) void cvt_x_kernel(
    const float* __restrict__ in, u16* __restrict__ out, int n)
{
    int i = (blockIdx.x * 256 + threadIdx.x) * 8;
    if (i < n) {
        f32x4 a = *(const f32x4*)(in + i);
        f32x4 b = *(const f32x4*)(in + i + 4);
        u16x8 o;
        #pragma unroll
        for (int j = 0; j < 4; ++j) { o[j] = f2bf(a[j]); o[j + 4] = f2bf(b[j]); }
        *(u16x8*)(out + i) = o;
    }
}

// in fp32 [K][N] (z-th slice from in0 if z<split else in1), out bf16 [N][K]
__global__ __launch_bounds__(256) void transpose_cvt(
    const float* __restrict__ in0, const float* __restrict__ in1,
    u16* __restrict__ out, int K, int N, int split)
{
    const int z = blockIdx.z;
    const float* in = (z < split) ? (in0 + (size_t)z * K * N)
                                  : (in1 + (size_t)(z - split) * K * N);
    u16* o = out + (size_t)z * N * K;

    __shared__ float tile[64][65];
    const int n0 = blockIdx.x * 64, k0 = blockIdx.y * 64;
    const int tx = threadIdx.x & 15;
    const int ty = threadIdx.x >> 4;

    #pragma unroll
    for (int p = 0; p < 4; ++p) {
        int k = ty + p * 16;
        f32x4 v = *(const f32x4*)(in + (size_t)(k0 + k) * N + n0 + tx * 4);
        *(f32x4*)&tile[k][tx * 4] = v;
    }
    __syncthreads();
    #pragma unroll
    for (int p = 0; p < 4; ++p) {
        int n = ty + p * 16;
        u16x4 w;
        #pragma unroll
        for (int j = 0; j < 4; ++j) w[j] = f2bf(tile[tx * 4 + j][n]);
        *(u16x4*)(o + (size_t)(n0 + n) * K + k0 + tx * 4) = w;
    }
}

// ---------------- fused gate+up GEMM: 128M x 64N, silu epilogue ----------------
// expert mode (counts!=null): grid(8, mTiles, N/64), e=bx, m=by, n=bz
// shared mode (counts==null): grid(8, mc,     N/64), e=0, m=bx*mc+by, n=bz
__global__ __launch_bounds__(256) void gemm_gu(
    const u16* __restrict__ A,
    const u16* __restrict__ Bg, const u16* __restrict__ Bu, size_t b_stride,
    u16* __restrict__ Hout,
    const int* __restrict__ a_ids, const int* __restrict__ seg_start,
    const int* __restrict__ counts,
    int K, int N, int Trows)
{
    int e, m_tile, cnt, base;
    if (counts) {
        e = blockIdx.x; m_tile = blockIdx.y;
        cnt = counts[e]; base = seg_start[e];
    } else {
        e = 0; m_tile = blockIdx.x * gridDim.y + blockIdx.y;
        cnt = Trows; base = 0;
    }
    const int m0 = m_tile * 128;
    if (m0 >= cnt) return;
    const int n0 = blockIdx.z * 64;
    const u16* Bge = Bg + (size_t)e * b_stride;
    const u16* Bue = Bu + (size_t)e * b_stride;

    __shared__ u16 As[128 * 32];
    __shared__ u16 Bgs[64 * 32];
    __shared__ u16 Bus[64 * 32];

    const int tid = threadIdx.x;
    const int st_row = tid >> 2;
    const int st_k   = (tid & 3) * 8;
    int ar0 = m0 + st_row;      if (ar0 >= cnt) ar0 = cnt - 1;
    int ar1 = m0 + st_row + 64; if (ar1 >= cnt) ar1 = cnt - 1;
    const int ga0 = a_ids ? a_ids[base + ar0] : (base + ar0);
    const int ga1 = a_ids ? a_ids[base + ar1] : (base + ar1);
    const u16* a0 = A + (size_t)ga0 * K + st_k;
    const u16* a1 = A + (size_t)ga1 * K + st_k;
    const u16* bg = Bge + (size_t)(n0 + st_row) * K + st_k;
    const u16* bu = Bue + (size_t)(n0 + st_row) * K + st_k;
    u16* as0 = As + tid * 8;
    u16* as1 = As + 2048 + tid * 8;
    u16* bgd = Bgs + tid * 8;
    u16* bud = Bus + tid * 8;

    f32x4 accG[4][2], accU[4][2];
    #pragma unroll
    for (int i = 0; i < 4; ++i)
        #pragma unroll
        for (int j = 0; j < 2; ++j) {
            accG[i][j] = (f32x4){0.f, 0.f, 0.f, 0.f};
            accU[i][j] = (f32x4){0.f, 0.f, 0.f, 0.f};
        }

    const int lane = tid & 63;
    const int wv = tid >> 6;
    const int wr = (wv >> 1) * 64;
    const int wc = (wv & 1) * 32;
    const int lrow = lane & 15;
    const int lkb = (lane >> 4) * 8;

    for (int k0 = 0; k0 < K; k0 += 32) {
        glds16(a0 + k0, as0);
        glds16(a1 + k0, as1);
        glds16(bg + k0, bgd);
        glds16(bu + k0, bud);
        __syncthreads();
        bf16x8 af[4], bgf[2], buf_[2];
        #pragma unroll
        for (int m = 0; m < 4; ++m)
            af[m] = *(const bf16x8*)&As[(wr + m * 16 + lrow) * 32 + lkb];
        #pragma unroll
        for (int n = 0; n < 2; ++n) {
            bgf[n]  = *(const bf16x8*)&Bgs[(wc + n * 16 + lrow) * 32 + lkb];
            buf_[n] = *(const bf16x8*)&Bus[(wc + n * 16 + lrow) * 32 + lkb];
        }
        #pragma unroll
        for (int m = 0; m < 4; ++m)
            #pragma unroll
            for (int n = 0; n < 2; ++n) {
                accG[m][n] = __builtin_amdgcn_mfma_f32_16x16x32_bf16(af[m], bgf[n],  accG[m][n], 0, 0, 0);
                accU[m][n] = __builtin_amdgcn_mfma_f32_16x16x32_bf16(af[m], buf_[n], accU[m][n], 0, 0, 0);
            }
        __syncthreads();
    }

    const int l4 = (lane >> 4) * 4;
    #pragma unroll
    for (int m = 0; m < 4; ++m)
        #pragma unroll
        for (int n = 0; n < 2; ++n)
            #pragma unroll
            for (int j = 0; j < 4; ++j) {
                int r = wr + m * 16 + l4 + j;
                if (m0 + r < cnt) {
                    int c = n0 + wc + n * 16 + lrow;
                    float g = accG[m][n][j], u = accU[m][n][j];
                    float hv = g / (1.f + __expf(-g)) * u;
                    Hout[(size_t)(base + m0 + r) * N + c] = f2bf(hv);
                }
            }
}

// ---------------- down GEMM: 128x128, raw fp32 store ----------------
// expert mode: grid(8, mTiles, N/128); shared mode: grid(8, mc, N/128)
__global__ __launch_bounds__(256) void gemm_down(
    const u16* __restrict__ A, const u16* __restrict__ B, size_t b_stride,
    float* __restrict__ Out,
    const int* __restrict__ seg_start, const int* __restrict__ counts,
    int K, int N, int Trows)
{
    int e, m_tile, cnt, base;
    if (counts) {
        e = blockIdx.x; m_tile = blockIdx.y;
        cnt = counts[e]; base = seg_start[e];
    } else {
        e = 0; m_tile = blockIdx.x * gridDim.y + blockIdx.y;
        cnt = Trows; base = 0;
    }
    const int m0 = m_tile * 128;
    if (m0 >= cnt) return;
    const int n0 = blockIdx.z * 128;
    const u16* Be = B + (size_t)e * b_stride;

    __shared__ u16 As[128 * 32];
    __shared__ u16 Bs[128 * 32];

    const int tid = threadIdx.x;
    const int st_row = tid >> 2;
    const int st_k   = (tid & 3) * 8;
    int ar0 = m0 + st_row;      if (ar0 >= cnt) ar0 = cnt - 1;
    int ar1 = m0 + st_row + 64; if (ar1 >= cnt) ar1 = cnt - 1;
    const u16* a0 = A + (size_t)(base + ar0) * K + st_k;
    const u16* a1 = A + (size_t)(base + ar1) * K + st_k;
    const u16* b0 = Be + (size_t)(n0 + st_row) * K + st_k;
    const u16* b1 = Be + (size_t)(n0 + st_row + 64) * K + st_k;
    u16* as0 = As + tid * 8;
    u16* as1 = As + 2048 + tid * 8;
    u16* bs0 = Bs + tid * 8;
    u16* bs1 = Bs + 2048 + tid * 8;

    f32x4 acc[4][4];
    #pragma unroll
    for (int i = 0; i < 4; ++i)
        #pragma unroll
        for (int j = 0; j < 4; ++j) acc[i][j] = (f32x4){0.f, 0.f, 0.f, 0.f};

    const int lane = tid & 63;
    const int wv = tid >> 6;
    const int wr = (wv >> 1) * 64;
    const int wc = (wv & 1) * 64;
    const int lrow = lane & 15;
    const int lkb = (lane >> 4) * 8;

    for (int k0 = 0; k0 < K; k0 += 32) {
        glds16(a0 + k0, as0);
        glds16(a1 + k0, as1);
        glds16(b0 + k0, bs0);
        glds16(b1 + k0, bs1);
        __syncthreads();
        bf16x8 af[4], bff[4];
        #pragma unroll
        for (int m = 0; m < 4; ++m)
            af[m] = *(const bf16x8*)&As[(wr + m * 16 + lrow) * 32 + lkb];
        #pragma unroll
        for (int n = 0; n < 4; ++n)
            bff[n] = *(const bf16x8*)&Bs[(wc + n * 16 + lrow) * 32 + lkb];
        #pragma unroll
        for (int m = 0; m < 4; ++m)
            #pragma unroll
            for (int n = 0; n < 4; ++n)
                acc[m][n] = __builtin_amdgcn_mfma_f32_16x16x32_bf16(af[m], bff[n], acc[m][n], 0, 0, 0);
        __syncthreads();
    }

    const int l4 = (lane >> 4) * 4;
    #pragma unroll
    for (int m = 0; m < 4; ++m)
        #pragma unroll
        for (int n = 0; n < 4; ++n)
            #pragma unroll
            for (int j = 0; j < 4; ++j) {
                int r = wr + m * 16 + l4 + j;
                if (m0 + r < cnt) {
                    int c = n0 + wc + n * 16 + lrow;
                    Out[(size_t)(base + m0 + r) * N + c] = acc[m][n][j];
                }
            }
}

// ---------------- combine: out = sgate*Dsh + w0*Dexp[s0] + w1*Dexp[s1] ----------------
__global__ __launch_bounds__(256) void combine_kernel(
    const float* __restrict__ Dexp, const float* __restrict__ Dsh,
    const int* __restrict__ slot, const float* __restrict__ topk_w,
    const float* __restrict__ sgate, float* __restrict__ Out)
{
    int idx = blockIdx.x * 256 + threadIdx.x;
    int t = idx >> 8;
    int c = (idx & 255) * 4;
    int s0 = slot[2 * t], s1 = slot[2 * t + 1];
    float w0 = topk_w[2 * t], w1 = topk_w[2 * t + 1], sg = sgate[t];
    f32x4 sh = *(const f32x4*)(Dsh + (size_t)t * HDIM + c);
    f32x4 d0 = *(const f32x4*)(Dexp + (size_t)s0 * HDIM + c);
    f32x4 d1 = *(const f32x4*)(Dexp + (size_t)s1 * HDIM + c);
    f32x4 o;
    #pragma unroll
    for (int j = 0; j < 4; ++j) o[j] = sg * sh[j] + w0 * d0[j] + w1 * d1[j];
    *(f32x4*)(Out + (size_t)t * HDIM + c) = o;
}

// ---------------- launch ----------------
extern "C" void kernel_launch(void* const* d_in, const int* in_sizes, int n_in,
                              void* d_out, int out_size, void* d_ws, size_t ws_size,
                              hipStream_t stream)
{
    const float* X   = (const float*)d_in[0];
    const float* GW  = (const float*)d_in[1];
    const float* WG  = (const float*)d_in[2];
    const float* WU  = (const float*)d_in[3];
    const float* WD  = (const float*)d_in[4];
    const float* SG  = (const float*)d_in[5];
    const float* SU  = (const float*)d_in[6];
    const float* SD  = (const float*)d_in[7];
    const float* SEG = (const float*)d_in[8];
    float* Out = (float*)d_out;

    char* ws = (char*)d_ws;
    int*   counts    = (int*)(ws + 0);
    int*   seg_start = (int*)(ws + 64);
    int*   cursors   = (int*)(ws + 128);
    int*   topk_e    = (int*)(ws + 1024);
    float* topk_w    = (float*)(ws + 1024 + 32768);
    float* sgate     = (float*)(ws + 1024 + 65536);
    int*   tok_ids   = (int*)(ws + 1024 + 65536 + 16384);
    int*   slot      = (int*)(ws + 1024 + 65536 + 16384 + 32768);

    u16* Xbf  = (u16*)(ws + 0x40000ull);     // 8.4 MB
    u16* Hact = (u16*)(ws + 0xA00000ull);    // 23.1 MB (slot-major [8192][1408])
    u16* Hs   = (u16*)(ws + 0x2200000ull);   // 23.1 MB ([4096][2816])
    u16* WGUt = (u16*)(ws + 0x3A00000ull);   // 46.1 MB (8x[I][H] gate, then 8x[I][H] up)
    u16* WDt  = (u16*)(ws + 0x6900000ull);   // 23.1 MB (8x[H][I])
    u16* SGUt = (u16*)(ws + 0x8100000ull);   // 11.5 MB ([IS][H] gate, up)
    u16* SDt  = (u16*)(ws + 0x8D00000ull);   // 5.8 MB ([H][IS])
    u16* WGt = WGUt;
    u16* WUt = WGUt + (size_t)NEXP * IDIM * HDIM;
    u16* SGt = SGUt;
    u16* SUt = SGUt + (size_t)ISDIM * HDIM;
    // aliases (stream-ordered reuse)
    float* Dexp = (float*)(ws + 0x3A00000ull);  // over WGUt, written after expert g/u done
    float* Dsh  = (float*)(ws + 0xA00000ull);   // over Hact, written after expert down done

    hipMemsetAsync(counts, 0, 64, stream);

    // routing
    route_kernel<<<T_TOK / 4, 256, 0, stream>>>(X, GW, SEG, topk_e, topk_w, sgate);
    hist_kernel<<<(T_TOK * 2) / 256, 256, 0, stream>>>(topk_e, counts);
    offsets_kernel<<<1, 64, 0, stream>>>(counts, seg_start, cursors);
    scatter_kernel<<<(T_TOK * 2) / 256, 256, 0, stream>>>(topk_e, cursors, tok_ids, slot);

    // converts
    cvt_x_kernel<<<(T_TOK * HDIM) / (256 * 8), 256, 0, stream>>>(X, Xbf, T_TOK * HDIM);
    transpose_cvt<<<dim3(IDIM / 64, HDIM / 64, 2 * NEXP), 256, 0, stream>>>(WG, WU, WGUt, HDIM, IDIM, NEXP);
    transpose_cvt<<<dim3(HDIM / 64, IDIM / 64, NEXP), 256, 0, stream>>>(WD, WD, WDt, IDIM, HDIM, NEXP);
    transpose_cvt<<<dim3(ISDIM / 64, HDIM / 64, 2), 256, 0, stream>>>(SG, SU, SGUt, HDIM, ISDIM, 1);
    transpose_cvt<<<dim3(HDIM / 64, ISDIM / 64, 1), 256, 0, stream>>>(SD, SD, SDt, ISDIM, HDIM, 1);

    // expert gate+up (XCD-affine: blockIdx.x = expert)
    gemm_gu<<<dim3(NEXP, T_TOK / 128, IDIM / 64), 256, 0, stream>>>(
        Xbf, WGt, WUt, (size_t)IDIM * HDIM, Hact,
        tok_ids, seg_start, counts, HDIM, IDIM, 0);
    // shared gate+up
    gemm_gu<<<dim3(8, T_TOK / 128 / 8, ISDIM / 64), 256, 0, stream>>>(
        Xbf, SGt, SUt, 0, Hs,
        nullptr, nullptr, nullptr, HDIM, ISDIM, T_TOK);
    // expert down -> Dexp (over WGUt; expert g/u already complete in stream order)
    gemm_down<<<dim3(NEXP, T_TOK / 128, HDIM / 128), 256, 0, stream>>>(
        Hact, WDt, (size_t)HDIM * IDIM, Dexp,
        seg_start, counts, IDIM, HDIM, 0);
    // shared down -> Dsh (over Hact; expert down already complete)
    gemm_down<<<dim3(8, T_TOK / 128 / 8, HDIM / 128), 256, 0, stream>>>(
        Hs, SDt, 0, Dsh,
        nullptr, nullptr, ISDIM, HDIM, T_TOK);
    // final combine
    combine_kernel<<<(T_TOK * HDIM / 4) / 256, 256, 0, stream>>>(
        Dexp, Dsh, slot, topk_w, sgate, Out);
}

// Round 5
// 376.481 us; speedup vs baseline: 1.9363x; 1.0145x over previous
//
#include <hip/hip_runtime.h>
#include <hip/hip_bf16.h>

#define T_TOK 4096
#define HDIM  1024
#define NEXP  8
#define IDIM  1408
#define ISDIM 2816

#define SWZ(r) (((r) ^ ((r) >> 2)) & 3)

typedef short bf16x8 __attribute__((ext_vector_type(8)));
typedef float f32x4  __attribute__((ext_vector_type(4)));
typedef unsigned short u16;
typedef unsigned short u16x4 __attribute__((ext_vector_type(4)));
typedef unsigned short u16x8 __attribute__((ext_vector_type(8)));

typedef __attribute__((address_space(1))) const void gvoid;
typedef __attribute__((address_space(3))) void lvoid;

__device__ __forceinline__ u16 f2bf(float f) {
    union { float f; unsigned u; } c; c.f = f;
    unsigned r = (c.u + 0x7FFFu + ((c.u >> 16) & 1u)) >> 16;
    return (u16)r;
}
__device__ __forceinline__ float bf2f(u16 v) {
    union { unsigned u; float f; } c; c.u = (unsigned)v << 16; return c.f;
}
__device__ __forceinline__ void glds16(const u16* g, u16* l) {
    __builtin_amdgcn_global_load_lds((gvoid*)g, (lvoid*)l, 16, 0, 0);
}

// ---------------- routing: one wave per token (no atomics) ----------------
__global__ __launch_bounds__(256) void route_kernel(
    const float* __restrict__ X, const float* __restrict__ GW,
    const float* __restrict__ SEG,
    int* __restrict__ topk_e, float* __restrict__ topk_w,
    float* __restrict__ sgate)
{
    const int t = blockIdx.x * 4 + (threadIdx.x >> 6);
    const int lane = threadIdx.x & 63;
    float acc[NEXP];
    #pragma unroll
    for (int e = 0; e < NEXP; ++e) acc[e] = 0.f;
    float sacc = 0.f;
    const float* xr = X + (size_t)t * HDIM;
    for (int h = lane; h < HDIM; h += 64) {
        float xv = xr[h];
        f32x4 g0 = *(const f32x4*)(GW + (size_t)h * NEXP);
        f32x4 g1 = *(const f32x4*)(GW + (size_t)h * NEXP + 4);
        acc[0] += xv * g0[0]; acc[1] += xv * g0[1];
        acc[2] += xv * g0[2]; acc[3] += xv * g0[3];
        acc[4] += xv * g1[0]; acc[5] += xv * g1[1];
        acc[6] += xv * g1[2]; acc[7] += xv * g1[3];
        sacc += xv * SEG[h];
    }
    #pragma unroll
    for (int off = 32; off > 0; off >>= 1) {
        #pragma unroll
        for (int e = 0; e < NEXP; ++e) acc[e] += __shfl_down(acc[e], off);
        sacc += __shfl_down(sacc, off);
    }
    if (lane == 0) {
        int e0 = 0;
        #pragma unroll
        for (int e = 1; e < NEXP; ++e) if (acc[e] > acc[e0]) e0 = e;
        int e1 = (e0 == 0) ? 1 : 0;
        #pragma unroll
        for (int e = 0; e < NEXP; ++e)
            if (e != e0 && acc[e] > acc[e1]) e1 = e;
        float w0 = 1.f / (1.f + __expf(acc[e1] - acc[e0]));
        topk_e[t * 2]     = e0; topk_e[t * 2 + 1] = e1;
        topk_w[t * 2]     = w0; topk_w[t * 2 + 1] = 1.f - w0;
        sgate[t] = 1.f / (1.f + __expf(-sacc));
    }
}

// ---------------- histogram: LDS-aggregated ----------------
__global__ __launch_bounds__(256) void hist_kernel(
    const int* __restrict__ topk_e, int* __restrict__ counts)
{
    __shared__ int h[NEXP];
    if (threadIdx.x < NEXP) h[threadIdx.x] = 0;
    __syncthreads();
    int i = blockIdx.x * 256 + threadIdx.x;
    atomicAdd(&h[topk_e[i]], 1);
    __syncthreads();
    if (threadIdx.x < NEXP) atomicAdd(&counts[threadIdx.x], h[threadIdx.x]);
}

__global__ void offsets_kernel(const int* __restrict__ counts,
                               int* __restrict__ seg_start,
                               int* __restrict__ cursors)
{
    if (threadIdx.x == 0) {
        int s = 0;
        for (int e = 0; e < NEXP; ++e) {
            seg_start[e] = s; cursors[e] = s; s += counts[e];
        }
    }
}

// ---------------- scatter: wave-ballot aggregated atomics + slot inverse map ----------------
__global__ __launch_bounds__(256) void scatter_kernel(
    const int* __restrict__ topk_e,
    int* __restrict__ cursors, int* __restrict__ tok_ids,
    int* __restrict__ slot)
{
    const int i = blockIdx.x * 256 + threadIdx.x;
    const int lane = threadIdx.x & 63;
    const int e = topk_e[i];
    const unsigned long long lt = (1ull << lane) - 1ull;
    #pragma unroll
    for (int ex = 0; ex < NEXP; ++ex) {
        unsigned long long mask = __ballot(e == ex);
        if (mask == 0ull) continue;
        int cnt = __popcll(mask);
        int leader = __ffsll((long long)mask) - 1;
        int base_ = 0;
        if (lane == leader) base_ = atomicAdd(&cursors[ex], cnt);
        base_ = __shfl(base_, leader);
        if (e == ex) {
            int pos = base_ + __popcll(mask & lt);
            tok_ids[pos] = i >> 1;
            slot[i] = pos;
        }
    }
}

// ---------------- converts ----------------
__global__ __launch_bounds__(256) void cvt_x_kernel(
    const float* __restrict__ in, u16* __restrict__ out, int n)
{
    int i = (blockIdx.x * 256 + threadIdx.x) * 8;
    if (i < n) {
        f32x4 a = *(const f32x4*)(in + i);
        f32x4 b = *(const f32x4*)(in + i + 4);
        u16x8 o;
        #pragma unroll
        for (int j = 0; j < 4; ++j) { o[j] = f2bf(a[j]); o[j + 4] = f2bf(b[j]); }
        *(u16x8*)(out + i) = o;
    }
}

// in fp32 [K][N] (z-th slice from in0 if z<split else in1), out bf16 [N][K]
__global__ __launch_bounds__(256) void transpose_cvt(
    const float* __restrict__ in0, const float* __restrict__ in1,
    u16* __restrict__ out, int K, int N, int split)
{
    const int z = blockIdx.z;
    const float* in = (z < split) ? (in0 + (size_t)z * K * N)
                                  : (in1 + (size_t)(z - split) * K * N);
    u16* o = out + (size_t)z * N * K;

    __shared__ float tile[64][65];
    const int n0 = blockIdx.x * 64, k0 = blockIdx.y * 64;
    const int tx = threadIdx.x & 15;
    const int ty = threadIdx.x >> 4;

    #pragma unroll
    for (int p = 0; p < 4; ++p) {
        int k = ty + p * 16;
        f32x4 v = *(const f32x4*)(in + (size_t)(k0 + k) * N + n0 + tx * 4);
        *(f32x4*)&tile[k][tx * 4] = v;
    }
    __syncthreads();
    #pragma unroll
    for (int p = 0; p < 4; ++p) {
        int n = ty + p * 16;
        u16x4 w;
        #pragma unroll
        for (int j = 0; j < 4; ++j) w[j] = f2bf(tile[tx * 4 + j][n]);
        *(u16x4*)(o + (size_t)(n0 + n) * K + k0 + tx * 4) = w;
    }
}

// ---------------- fused gate+up GEMM: 128M x 64N, dbuf + swizzle, silu epilogue ----------------
// zz < 176: expert (e = zz&7, n-tile = zz>>3); zz in [176,180): pad (return);
// zz >= 180: shared (n-tile = zz-180). grid(224, 32).
__global__ __launch_bounds__(256) void gemm_gu(
    const u16* __restrict__ A,
    const u16* __restrict__ WGt, const u16* __restrict__ WUt,
    const u16* __restrict__ SGt, const u16* __restrict__ SUt,
    u16* __restrict__ HoutE, u16* __restrict__ HoutS,
    const int* __restrict__ a_ids, const int* __restrict__ seg_start,
    const int* __restrict__ counts)
{
    const int zz = blockIdx.x;
    if (zz >= 176 && zz < 180) return;
    const bool shr = (zz >= 180);
    int n0, cnt, base, N;
    const u16 *Bg, *Bu;
    u16* Hout;
    if (!shr) {
        int e = zz & 7;
        n0 = (zz >> 3) * 64;
        cnt = counts[e]; base = seg_start[e];
        Bg = WGt + (size_t)e * (IDIM * HDIM);
        Bu = WUt + (size_t)e * (IDIM * HDIM);
        Hout = HoutE; N = IDIM;
    } else {
        n0 = (zz - 180) * 64;
        cnt = T_TOK; base = 0;
        Bg = SGt; Bu = SUt;
        Hout = HoutS; N = ISDIM;
    }
    const int m0 = blockIdx.y * 128;
    if (m0 >= cnt) return;
    const int K = HDIM;

    __shared__ u16 As[2][4096];   // [row 0..127][k 0..31], swizzled slots
    __shared__ u16 Bs[2][4096];   // rows 0..63 gate, 64..127 up

    const int tid = threadIdx.x;
    const int srow = tid >> 2;
    const int st_k = ((tid & 3) ^ SWZ(srow)) * 8;
    int ar0 = m0 + srow;       if (ar0 >= cnt) ar0 = cnt - 1;
    int ar1 = m0 + srow + 64;  if (ar1 >= cnt) ar1 = cnt - 1;
    const int ga0 = shr ? ar0 : a_ids[base + ar0];
    const int ga1 = shr ? ar1 : a_ids[base + ar1];
    const u16* a0 = A + (size_t)ga0 * K + st_k;
    const u16* a1 = A + (size_t)ga1 * K + st_k;
    const u16* bg = Bg + (size_t)(n0 + srow) * K + st_k;
    const u16* bu = Bu + (size_t)(n0 + srow) * K + st_k;

    f32x4 accG[4][2], accU[4][2];
    #pragma unroll
    for (int i = 0; i < 4; ++i)
        #pragma unroll
        for (int j = 0; j < 2; ++j) {
            accG[i][j] = (f32x4){0.f, 0.f, 0.f, 0.f};
            accU[i][j] = (f32x4){0.f, 0.f, 0.f, 0.f};
        }

    const int lane = tid & 63;
    const int wv = tid >> 6;
    const int wr = (wv >> 1) * 64;
    const int wc = (wv & 1) * 32;
    const int lrow = lane & 15;
    const int kslot = lane >> 4;

    int offA[4], offBg[2], offBu[2];
    #pragma unroll
    for (int m = 0; m < 4; ++m) {
        int r = wr + m * 16 + lrow;
        offA[m] = r * 32 + ((kslot ^ SWZ(r)) * 8);
    }
    #pragma unroll
    for (int n = 0; n < 2; ++n) {
        int r = wc + n * 16 + lrow;
        offBg[n] = r * 32 + ((kslot ^ SWZ(r)) * 8);
        offBu[n] = offBg[n] + 2048;
    }

    #define STAGE_GU(b, off) \
        glds16(a0 + (off), &As[b][tid * 8]); \
        glds16(a1 + (off), &As[b][2048 + tid * 8]); \
        glds16(bg + (off), &Bs[b][tid * 8]); \
        glds16(bu + (off), &Bs[b][2048 + tid * 8]);

    STAGE_GU(0, 0)
    __syncthreads();
    int cur = 0;
    #pragma unroll 1
    for (int t = 0; t < K / 32 - 1; ++t) {
        STAGE_GU(cur ^ 1, (t + 1) * 32)
        const u16* Ac = As[cur];
        const u16* Bc = Bs[cur];
        bf16x8 af[4], bgf[2], buf_[2];
        #pragma unroll
        for (int m = 0; m < 4; ++m) af[m] = *(const bf16x8*)&Ac[offA[m]];
        #pragma unroll
        for (int n = 0; n < 2; ++n) {
            bgf[n]  = *(const bf16x8*)&Bc[offBg[n]];
            buf_[n] = *(const bf16x8*)&Bc[offBu[n]];
        }
        #pragma unroll
        for (int m = 0; m < 4; ++m)
            #pragma unroll
            for (int n = 0; n < 2; ++n) {
                accG[m][n] = __builtin_amdgcn_mfma_f32_16x16x32_bf16(af[m], bgf[n],  accG[m][n], 0, 0, 0);
                accU[m][n] = __builtin_amdgcn_mfma_f32_16x16x32_bf16(af[m], buf_[n], accU[m][n], 0, 0, 0);
            }
        __syncthreads();
        cur ^= 1;
    }
    {
        const u16* Ac = As[cur];
        const u16* Bc = Bs[cur];
        bf16x8 af[4], bgf[2], buf_[2];
        #pragma unroll
        for (int m = 0; m < 4; ++m) af[m] = *(const bf16x8*)&Ac[offA[m]];
        #pragma unroll
        for (int n = 0; n < 2; ++n) {
            bgf[n]  = *(const bf16x8*)&Bc[offBg[n]];
            buf_[n] = *(const bf16x8*)&Bc[offBu[n]];
        }
        #pragma unroll
        for (int m = 0; m < 4; ++m)
            #pragma unroll
            for (int n = 0; n < 2; ++n) {
                accG[m][n] = __builtin_amdgcn_mfma_f32_16x16x32_bf16(af[m], bgf[n],  accG[m][n], 0, 0, 0);
                accU[m][n] = __builtin_amdgcn_mfma_f32_16x16x32_bf16(af[m], buf_[n], accU[m][n], 0, 0, 0);
            }
    }

    const int l4 = (lane >> 4) * 4;
    #pragma unroll
    for (int m = 0; m < 4; ++m)
        #pragma unroll
        for (int n = 0; n < 2; ++n)
            #pragma unroll
            for (int j = 0; j < 4; ++j) {
                int r = wr + m * 16 + l4 + j;
                if (m0 + r < cnt) {
                    int c = n0 + wc + n * 16 + lrow;
                    float g = accG[m][n][j], u = accU[m][n][j];
                    float hv = g / (1.f + __expf(-g)) * u;
                    Hout[(size_t)(base + m0 + r) * N + c] = f2bf(hv);
                }
            }
}

// ---------------- down GEMM: 128x128, dbuf + swizzle, fp32 store ----------------
// zz < 64: expert (e = zz&7, n-tile = zz>>3, K=IDIM, A=HactE, Out=Dexp);
// zz in [64,72): shared (n-tile = zz-64, K=ISDIM, A=Hs, Out=OutS). grid(72, 32).
__global__ __launch_bounds__(256) void gemm_down(
    const u16* __restrict__ AE, const u16* __restrict__ AS,
    const u16* __restrict__ WDt, const u16* __restrict__ SDt,
    float* __restrict__ DexpO, float* __restrict__ OutS,
    const int* __restrict__ seg_start, const int* __restrict__ counts)
{
    const int zz = blockIdx.x;
    const bool shr = (zz >= 64);
    int n0, cnt, base, K;
    const u16 *Ab, *Be;
    float* Outp;
    if (!shr) {
        int e = zz & 7;
        n0 = (zz >> 3) * 128;
        cnt = counts[e]; base = seg_start[e];
        Ab = AE; Be = WDt + (size_t)e * (HDIM * IDIM);
        Outp = DexpO; K = IDIM;
    } else {
        n0 = (zz - 64) * 128;
        cnt = T_TOK; base = 0;
        Ab = AS; Be = SDt;
        Outp = OutS; K = ISDIM;
    }
    const int m0 = blockIdx.y * 128;
    if (m0 >= cnt) return;

    __shared__ u16 As[2][4096];
    __shared__ u16 Bs[2][4096];

    const int tid = threadIdx.x;
    const int srow = tid >> 2;
    const int st_k = ((tid & 3) ^ SWZ(srow)) * 8;
    int ar0 = m0 + srow;       if (ar0 >= cnt) ar0 = cnt - 1;
    int ar1 = m0 + srow + 64;  if (ar1 >= cnt) ar1 = cnt - 1;
    const u16* a0 = Ab + (size_t)(base + ar0) * K + st_k;
    const u16* a1 = Ab + (size_t)(base + ar1) * K + st_k;
    const u16* b0 = Be + (size_t)(n0 + srow) * K + st_k;
    const u16* b1 = Be + (size_t)(n0 + srow + 64) * K + st_k;

    f32x4 acc[4][4];
    #pragma unroll
    for (int i = 0; i < 4; ++i)
        #pragma unroll
        for (int j = 0; j < 4; ++j) acc[i][j] = (f32x4){0.f, 0.f, 0.f, 0.f};

    const int lane = tid & 63;
    const int wv = tid >> 6;
    const int wr = (wv >> 1) * 64;
    const int wc = (wv & 1) * 64;
    const int lrow = lane & 15;
    const int kslot = lane >> 4;

    int offA[4], offB[4];
    #pragma unroll
    for (int m = 0; m < 4; ++m) {
        int r = wr + m * 16 + lrow;
        offA[m] = r * 32 + ((kslot ^ SWZ(r)) * 8);
    }
    #pragma unroll
    for (int n = 0; n < 4; ++n) {
        int r = wc + n * 16 + lrow;
        offB[n] = r * 32 + ((kslot ^ SWZ(r)) * 8);
    }

    #define STAGE_DN(b, off) \
        glds16(a0 + (off), &As[b][tid * 8]); \
        glds16(a1 + (off), &As[b][2048 + tid * 8]); \
        glds16(b0 + (off), &Bs[b][tid * 8]); \
        glds16(b1 + (off), &Bs[b][2048 + tid * 8]);

    STAGE_DN(0, 0)
    __syncthreads();
    int cur = 0;
    const int NT = K / 32;
    #pragma unroll 1
    for (int t = 0; t < NT - 1; ++t) {
        STAGE_DN(cur ^ 1, (t + 1) * 32)
        const u16* Ac = As[cur];
        const u16* Bc = Bs[cur];
        bf16x8 af[4], bff[4];
        #pragma unroll
        for (int m = 0; m < 4; ++m) af[m] = *(const bf16x8*)&Ac[offA[m]];
        #pragma unroll
        for (int n = 0; n < 4; ++n) bff[n] = *(const bf16x8*)&Bc[offB[n]];
        #pragma unroll
        for (int m = 0; m < 4; ++m)
            #pragma unroll
            for (int n = 0; n < 4; ++n)
                acc[m][n] = __builtin_amdgcn_mfma_f32_16x16x32_bf16(af[m], bff[n], acc[m][n], 0, 0, 0);
        __syncthreads();
        cur ^= 1;
    }
    {
        const u16* Ac = As[cur];
        const u16* Bc = Bs[cur];
        bf16x8 af[4], bff[4];
        #pragma unroll
        for (int m = 0; m < 4; ++m) af[m] = *(const bf16x8*)&Ac[offA[m]];
        #pragma unroll
        for (int n = 0; n < 4; ++n) bff[n] = *(const bf16x8*)&Bc[offB[n]];
        #pragma unroll
        for (int m = 0; m < 4; ++m)
            #pragma unroll
            for (int n = 0; n < 4; ++n)
                acc[m][n] = __builtin_amdgcn_mfma_f32_16x16x32_bf16(af[m], bff[n], acc[m][n], 0, 0, 0);
    }

    const int l4 = (lane >> 4) * 4;
    #pragma unroll
    for (int m = 0; m < 4; ++m)
        #pragma unroll
        for (int n = 0; n < 4; ++n)
            #pragma unroll
            for (int j = 0; j < 4; ++j) {
                int r = wr + m * 16 + l4 + j;
                if (m0 + r < cnt) {
                    int c = n0 + wc + n * 16 + lrow;
                    Outp[(size_t)(base + m0 + r) * HDIM + c] = acc[m][n][j];
                }
            }
}

// ---------------- combine: out = sgate*out + w0*Dexp[s0] + w1*Dexp[s1] ----------------
__global__ __launch_bounds__(256) void combine_kernel(
    const float* __restrict__ Dexp,
    const int* __restrict__ slot, const float* __restrict__ topk_w,
    const float* __restrict__ sgate, float* __restrict__ Out)
{
    int idx = blockIdx.x * 256 + threadIdx.x;
    int t = idx >> 8;
    int c = (idx & 255) * 4;
    int s0 = slot[2 * t], s1 = slot[2 * t + 1];
    float w0 = topk_w[2 * t], w1 = topk_w[2 * t + 1], sg = sgate[t];
    f32x4 sh = *(const f32x4*)(Out + (size_t)t * HDIM + c);
    f32x4 d0 = *(const f32x4*)(Dexp + (size_t)s0 * HDIM + c);
    f32x4 d1 = *(const f32x4*)(Dexp + (size_t)s1 * HDIM + c);
    f32x4 o;
    #pragma unroll
    for (int j = 0; j < 4; ++j) o[j] = sg * sh[j] + w0 * d0[j] + w1 * d1[j];
    *(f32x4*)(Out + (size_t)t * HDIM + c) = o;
}

// ---------------- launch ----------------
extern "C" void kernel_launch(void* const* d_in, const int* in_sizes, int n_in,
                              void* d_out, int out_size, void* d_ws, size_t ws_size,
                              hipStream_t stream)
{
    const float* X   = (const float*)d_in[0];
    const float* GW  = (const float*)d_in[1];
    const float* WG  = (const float*)d_in[2];
    const float* WU  = (const float*)d_in[3];
    const float* WD  = (const float*)d_in[4];
    const float* SG  = (const float*)d_in[5];
    const float* SU  = (const float*)d_in[6];
    const float* SD  = (const float*)d_in[7];
    const float* SEG = (const float*)d_in[8];
    float* Out = (float*)d_out;

    char* ws = (char*)d_ws;
    int*   counts    = (int*)(ws + 0);
    int*   seg_start = (int*)(ws + 64);
    int*   cursors   = (int*)(ws + 128);
    int*   topk_e    = (int*)(ws + 1024);
    float* topk_w    = (float*)(ws + 1024 + 32768);
    float* sgate     = (float*)(ws + 1024 + 65536);
    int*   tok_ids   = (int*)(ws + 1024 + 65536 + 16384);
    int*   slot      = (int*)(ws + 1024 + 65536 + 16384 + 32768);

    u16* Xbf  = (u16*)(ws + 0x40000ull);     // 8.4 MB
    u16* Hact = (u16*)(ws + 0xA00000ull);    // 23.1 MB (slot-major [8192][1408])
    u16* Hs   = (u16*)(ws + 0x2200000ull);   // 23.1 MB ([4096][2816])
    u16* WGUt = (u16*)(ws + 0x3A00000ull);   // 46.1 MB (8x[I][H] gate, then 8x[I][H] up)
    u16* WDt  = (u16*)(ws + 0x6900000ull);   // 23.1 MB (8x[H][I])
    u16* SGUt = (u16*)(ws + 0x8100000ull);   // 11.5 MB ([IS][H] gate, up)
    u16* SDt  = (u16*)(ws + 0x8D00000ull);   // 5.8 MB ([H][IS])
    u16* WGt = WGUt;
    u16* WUt = WGUt + (size_t)NEXP * IDIM * HDIM;
    u16* SGt = SGUt;
    u16* SUt = SGUt + (size_t)ISDIM * HDIM;
    // Dexp aliases WGUt (needs 33.5 MB <= 46.1 MB); written only after gemm_gu done
    float* Dexp = (float*)(ws + 0x3A00000ull);

    hipMemsetAsync(counts, 0, 64, stream);

    // routing
    route_kernel<<<T_TOK / 4, 256, 0, stream>>>(X, GW, SEG, topk_e, topk_w, sgate);
    hist_kernel<<<(T_TOK * 2) / 256, 256, 0, stream>>>(topk_e, counts);
    offsets_kernel<<<1, 64, 0, stream>>>(counts, seg_start, cursors);
    scatter_kernel<<<(T_TOK * 2) / 256, 256, 0, stream>>>(topk_e, cursors, tok_ids, slot);

    // converts
    cvt_x_kernel<<<(T_TOK * HDIM) / (256 * 8), 256, 0, stream>>>(X, Xbf, T_TOK * HDIM);
    transpose_cvt<<<dim3(IDIM / 64, HDIM / 64, 2 * NEXP), 256, 0, stream>>>(WG, WU, WGUt, HDIM, IDIM, NEXP);
    transpose_cvt<<<dim3(HDIM / 64, IDIM / 64, NEXP), 256, 0, stream>>>(WD, WD, WDt, IDIM, HDIM, NEXP);
    transpose_cvt<<<dim3(ISDIM / 64, HDIM / 64, 2), 256, 0, stream>>>(SG, SU, SGUt, HDIM, ISDIM, 1);
    transpose_cvt<<<dim3(HDIM / 64, ISDIM / 64, 1), 256, 0, stream>>>(SD, SD, SDt, ISDIM, HDIM, 1);

    // merged gate+up (experts XCD-pinned via zz%8, shared spread)
    gemm_gu<<<dim3(224, T_TOK / 128), 256, 0, stream>>>(
        Xbf, WGt, WUt, SGt, SUt, Hact, Hs,
        tok_ids, seg_start, counts);

    // merged down: expert -> Dexp (raw), shared -> Out (raw)
    gemm_down<<<dim3(72, T_TOK / 128), 256, 0, stream>>>(
        Hact, Hs, WDt, SDt, Dexp, Out,
        seg_start, counts);

    // final combine (reads shared value from Out, rewrites Out)
    combine_kernel<<<(T_TOK * HDIM / 4) / 256, 256, 0, stream>>>(
        Dexp, slot, topk_w, sgate, Out);
}

// Round 6
// 353.166 us; speedup vs baseline: 2.0642x; 1.0660x over previous
//
#include <hip/hip_runtime.h>
#include <hip/hip_bf16.h>

#define T_TOK 4096
#define HDIM  1024
#define NEXP  8
#define IDIM  1408
#define ISDIM 2816

typedef short bf16x8 __attribute__((ext_vector_type(8)));
typedef float f32x4  __attribute__((ext_vector_type(4)));
typedef unsigned short u16;
typedef unsigned short u16x4 __attribute__((ext_vector_type(4)));
typedef unsigned short u16x8 __attribute__((ext_vector_type(8)));

typedef __attribute__((address_space(1))) const void gvoid;
typedef __attribute__((address_space(3))) void lvoid;

__device__ __forceinline__ u16 f2bf(float f) {
    union { float f; unsigned u; } c; c.f = f;
    unsigned r = (c.u + 0x7FFFu + ((c.u >> 16) & 1u)) >> 16;
    return (u16)r;
}
__device__ __forceinline__ float bf2f(u16 v) {
    union { unsigned u; float f; } c; c.u = (unsigned)v << 16; return c.f;
}
__device__ __forceinline__ void glds16(const u16* g, u16* l) {
    __builtin_amdgcn_global_load_lds((gvoid*)g, (lvoid*)l, 16, 0, 0);
}

// ---------------- routing: one wave per token (no atomics) ----------------
__global__ __launch_bounds__(256) void route_kernel(
    const float* __restrict__ X, const float* __restrict__ GW,
    const float* __restrict__ SEG,
    int* __restrict__ topk_e, float* __restrict__ topk_w,
    float* __restrict__ sgate)
{
    const int t = blockIdx.x * 4 + (threadIdx.x >> 6);
    const int lane = threadIdx.x & 63;
    float acc[NEXP];
    #pragma unroll
    for (int e = 0; e < NEXP; ++e) acc[e] = 0.f;
    float sacc = 0.f;
    const float* xr = X + (size_t)t * HDIM;
    for (int h = lane; h < HDIM; h += 64) {
        float xv = xr[h];
        f32x4 g0 = *(const f32x4*)(GW + (size_t)h * NEXP);
        f32x4 g1 = *(const f32x4*)(GW + (size_t)h * NEXP + 4);
        acc[0] += xv * g0[0]; acc[1] += xv * g0[1];
        acc[2] += xv * g0[2]; acc[3] += xv * g0[3];
        acc[4] += xv * g1[0]; acc[5] += xv * g1[1];
        acc[6] += xv * g1[2]; acc[7] += xv * g1[3];
        sacc += xv * SEG[h];
    }
    #pragma unroll
    for (int off = 32; off > 0; off >>= 1) {
        #pragma unroll
        for (int e = 0; e < NEXP; ++e) acc[e] += __shfl_down(acc[e], off);
        sacc += __shfl_down(sacc, off);
    }
    if (lane == 0) {
        int e0 = 0;
        #pragma unroll
        for (int e = 1; e < NEXP; ++e) if (acc[e] > acc[e0]) e0 = e;
        int e1 = (e0 == 0) ? 1 : 0;
        #pragma unroll
        for (int e = 0; e < NEXP; ++e)
            if (e != e0 && acc[e] > acc[e1]) e1 = e;
        float w0 = 1.f / (1.f + __expf(acc[e1] - acc[e0]));
        topk_e[t * 2]     = e0; topk_e[t * 2 + 1] = e1;
        topk_w[t * 2]     = w0; topk_w[t * 2 + 1] = 1.f - w0;
        sgate[t] = 1.f / (1.f + __expf(-sacc));
    }
}

// ---------------- histogram: LDS-aggregated ----------------
__global__ __launch_bounds__(256) void hist_kernel(
    const int* __restrict__ topk_e, int* __restrict__ counts)
{
    __shared__ int h[NEXP];
    if (threadIdx.x < NEXP) h[threadIdx.x] = 0;
    __syncthreads();
    int i = blockIdx.x * 256 + threadIdx.x;
    atomicAdd(&h[topk_e[i]], 1);
    __syncthreads();
    if (threadIdx.x < NEXP) atomicAdd(&counts[threadIdx.x], h[threadIdx.x]);
}

__global__ void offsets_kernel(const int* __restrict__ counts,
                               int* __restrict__ seg_start,
                               int* __restrict__ cursors)
{
    if (threadIdx.x == 0) {
        int s = 0;
        for (int e = 0; e < NEXP; ++e) {
            seg_start[e] = s; cursors[e] = s; s += counts[e];
        }
    }
}

// ---------------- scatter: wave-ballot aggregated atomics + slot inverse map ----------------
__global__ __launch_bounds__(256) void scatter_kernel(
    const int* __restrict__ topk_e,
    int* __restrict__ cursors, int* __restrict__ tok_ids,
    int* __restrict__ slot)
{
    const int i = blockIdx.x * 256 + threadIdx.x;
    const int lane = threadIdx.x & 63;
    const int e = topk_e[i];
    const unsigned long long lt = (1ull << lane) - 1ull;
    #pragma unroll
    for (int ex = 0; ex < NEXP; ++ex) {
        unsigned long long mask = __ballot(e == ex);
        if (mask == 0ull) continue;
        int cnt = __popcll(mask);
        int leader = __ffsll((long long)mask) - 1;
        int base_ = 0;
        if (lane == leader) base_ = atomicAdd(&cursors[ex], cnt);
        base_ = __shfl(base_, leader);
        if (e == ex) {
            int pos = base_ + __popcll(mask & lt);
            tok_ids[pos] = i >> 1;
            slot[i] = pos;
        }
    }
}

// ---------------- converts ----------------
__global__ __launch_bounds__(256) void cvt_x_kernel(
    const float* __restrict__ in, u16* __restrict__ out, int n)
{
    int i = (blockIdx.x * 256 + threadIdx.x) * 8;
    if (i < n) {
        f32x4 a = *(const f32x4*)(in + i);
        f32x4 b = *(const f32x4*)(in + i + 4);
        u16x8 o;
        #pragma unroll
        for (int j = 0; j < 4; ++j) { o[j] = f2bf(a[j]); o[j + 4] = f2bf(b[j]); }
        *(u16x8*)(out + i) = o;
    }
}

// in fp32 [K][N] (z-th slice from in0 if z<split else in1), out bf16 [N][K]
__global__ __launch_bounds__(256) void transpose_cvt(
    const float* __restrict__ in0, const float* __restrict__ in1,
    u16* __restrict__ out, int K, int N, int split)
{
    const int z = blockIdx.z;
    const float* in = (z < split) ? (in0 + (size_t)z * K * N)
                                  : (in1 + (size_t)(z - split) * K * N);
    u16* o = out + (size_t)z * N * K;

    __shared__ float tile[64][65];
    const int n0 = blockIdx.x * 64, k0 = blockIdx.y * 64;
    const int tx = threadIdx.x & 15;
    const int ty = threadIdx.x >> 4;

    #pragma unroll
    for (int p = 0; p < 4; ++p) {
        int k = ty + p * 16;
        f32x4 v = *(const f32x4*)(in + (size_t)(k0 + k) * N + n0 + tx * 4);
        *(f32x4*)&tile[k][tx * 4] = v;
    }
    __syncthreads();
    #pragma unroll
    for (int p = 0; p < 4; ++p) {
        int n = ty + p * 16;
        u16x4 w;
        #pragma unroll
        for (int j = 0; j < 4; ++j) w[j] = f2bf(tile[tx * 4 + j][n]);
        *(u16x4*)(o + (size_t)(n0 + n) * K + k0 + tx * 4) = w;
    }
}

// ---------------- fused gate+up GEMM: 128M x 64N, counted-vmcnt dbuf, silu epilogue ----------------
// expert mode (counts!=null): grid(8, 32, 22): e=bx, m=by, n=bz
// shared mode (counts==null): grid(8, 4, 44): m = bx*4+by, n=bz
__global__ __launch_bounds__(256) void gemm_gu(
    const u16* __restrict__ A,
    const u16* __restrict__ Bg_, const u16* __restrict__ Bu_, size_t b_stride,
    u16* __restrict__ Hout,
    const int* __restrict__ a_ids, const int* __restrict__ seg_start,
    const int* __restrict__ counts,
    int N, int Trows)
{
    int e, m_tile, cnt, base;
    if (counts) {
        e = blockIdx.x; m_tile = blockIdx.y;
        cnt = counts[e]; base = seg_start[e];
    } else {
        e = 0; m_tile = blockIdx.x * gridDim.y + blockIdx.y;
        cnt = Trows; base = 0;
    }
    const int m0 = m_tile * 128;
    if (m0 >= cnt) return;
    const int n0 = blockIdx.z * 64;
    const u16* Bg = Bg_ + (size_t)e * b_stride;
    const u16* Bu = Bu_ + (size_t)e * b_stride;
    const int K = HDIM;   // 1024 -> NT = 32

    __shared__ u16 As[2 * 4096];   // [buf][row 0..127][k 0..31]
    __shared__ u16 Bs[2 * 4096];   // [buf][rows 0..63 gate | 64..127 up][k]

    const int tid = threadIdx.x;
    const int srow = tid >> 2;
    const int st_k = (tid & 3) * 8;
    int ar0 = m0 + srow;       if (ar0 >= cnt) ar0 = cnt - 1;
    int ar1 = m0 + srow + 64;  if (ar1 >= cnt) ar1 = cnt - 1;
    const int ga0 = a_ids ? a_ids[base + ar0] : (base + ar0);
    const int ga1 = a_ids ? a_ids[base + ar1] : (base + ar1);
    const u16* a0 = A + (size_t)ga0 * K + st_k;
    const u16* a1 = A + (size_t)ga1 * K + st_k;
    const u16* bg = Bg + (size_t)(n0 + srow) * K + st_k;
    const u16* bu = Bu + (size_t)(n0 + srow) * K + st_k;

    f32x4 accG[4][2], accU[4][2];
    #pragma unroll
    for (int i = 0; i < 4; ++i)
        #pragma unroll
        for (int j = 0; j < 2; ++j) {
            accG[i][j] = (f32x4){0.f, 0.f, 0.f, 0.f};
            accU[i][j] = (f32x4){0.f, 0.f, 0.f, 0.f};
        }

    const int lane = tid & 63;
    const int wv = tid >> 6;
    const int wr = (wv >> 1) * 64;
    const int wc = (wv & 1) * 32;
    const int lrow = lane & 15;
    const int lkb = (lane >> 4) * 8;

    int offA[4], offBg[2];
    #pragma unroll
    for (int m = 0; m < 4; ++m) offA[m] = (wr + m * 16 + lrow) * 32 + lkb;
    #pragma unroll
    for (int n = 0; n < 2; ++n) offBg[n] = (wc + n * 16 + lrow) * 32 + lkb;

#define STAGE_GU(ps) do { \
    glds16(a0, &As[(ps) + tid * 8]); \
    glds16(a1, &As[(ps) + 2048 + tid * 8]); \
    glds16(bg, &Bs[(ps) + tid * 8]); \
    glds16(bu, &Bs[(ps) + 2048 + tid * 8]); \
    a0 += 32; a1 += 32; bg += 32; bu += 32; } while (0)

#define COMPUTE_GU(ps) do { \
    bf16x8 af[4], bgf[2], bux[2]; \
    _Pragma("unroll") for (int m = 0; m < 4; ++m) af[m] = *(const bf16x8*)&As[(ps) + offA[m]]; \
    _Pragma("unroll") for (int n = 0; n < 2; ++n) { \
        bgf[n] = *(const bf16x8*)&Bs[(ps) + offBg[n]]; \
        bux[n] = *(const bf16x8*)&Bs[(ps) + offBg[n] + 2048]; } \
    _Pragma("unroll") for (int m = 0; m < 4; ++m) \
        _Pragma("unroll") for (int n = 0; n < 2; ++n) { \
            accG[m][n] = __builtin_amdgcn_mfma_f32_16x16x32_bf16(af[m], bgf[n], accG[m][n], 0, 0, 0); \
            accU[m][n] = __builtin_amdgcn_mfma_f32_16x16x32_bf16(af[m], bux[n], accU[m][n], 0, 0, 0); } \
    } while (0)

    STAGE_GU(0);
    STAGE_GU(4096);
    #pragma unroll 1
    for (int t = 0; t < 30; ++t) {
        asm volatile("s_waitcnt vmcnt(4)" ::: "memory");
        __builtin_amdgcn_s_barrier();
        const int ps = (t & 1) * 4096;
        COMPUTE_GU(ps);
        __builtin_amdgcn_s_barrier();
        STAGE_GU(ps);
    }
    asm volatile("s_waitcnt vmcnt(4)" ::: "memory");
    __builtin_amdgcn_s_barrier();
    COMPUTE_GU(0);
    asm volatile("s_waitcnt vmcnt(0)" ::: "memory");
    __builtin_amdgcn_s_barrier();
    COMPUTE_GU(4096);

    const int l4 = (lane >> 4) * 4;
    #pragma unroll
    for (int m = 0; m < 4; ++m)
        #pragma unroll
        for (int n = 0; n < 2; ++n)
            #pragma unroll
            for (int j = 0; j < 4; ++j) {
                int r = wr + m * 16 + l4 + j;
                if (m0 + r < cnt) {
                    int c = n0 + wc + n * 16 + lrow;
                    float g = accG[m][n][j], u = accU[m][n][j];
                    float hv = g / (1.f + __expf(-g)) * u;
                    Hout[(size_t)(base + m0 + r) * N + c] = f2bf(hv);
                }
            }
}

// ---------------- down GEMM: 128x128, counted-vmcnt dbuf, fp32 store ----------------
// zz < 64: expert (e = zz&7, n-tile = zz>>3, K=IDIM, A=Hact, Out=Dexp);
// zz in [64,72): shared (n-tile = zz-64, K=ISDIM, A=Hs, Out=Out). grid(72, 32).
__global__ __launch_bounds__(256) void gemm_down(
    const u16* __restrict__ AE, const u16* __restrict__ AS,
    const u16* __restrict__ WDt, const u16* __restrict__ SDt,
    float* __restrict__ DexpO, float* __restrict__ OutS,
    const int* __restrict__ seg_start, const int* __restrict__ counts)
{
    const int zz = blockIdx.x;
    const bool shr = (zz >= 64);
    int n0, cnt, base, K;
    const u16 *Ab, *Be;
    float* Outp;
    if (!shr) {
        int e = zz & 7;
        n0 = (zz >> 3) * 128;
        cnt = counts[e]; base = seg_start[e];
        Ab = AE; Be = WDt + (size_t)e * (HDIM * IDIM);
        Outp = DexpO; K = IDIM;     // NT = 44
    } else {
        n0 = (zz - 64) * 128;
        cnt = T_TOK; base = 0;
        Ab = AS; Be = SDt;
        Outp = OutS; K = ISDIM;     // NT = 88
    }
    const int m0 = blockIdx.y * 128;
    if (m0 >= cnt) return;
    const int NT = K / 32;

    __shared__ u16 As[2 * 4096];
    __shared__ u16 Bs[2 * 4096];

    const int tid = threadIdx.x;
    const int srow = tid >> 2;
    const int st_k = (tid & 3) * 8;
    int ar0 = m0 + srow;       if (ar0 >= cnt) ar0 = cnt - 1;
    int ar1 = m0 + srow + 64;  if (ar1 >= cnt) ar1 = cnt - 1;
    const u16* a0 = Ab + (size_t)(base + ar0) * K + st_k;
    const u16* a1 = Ab + (size_t)(base + ar1) * K + st_k;
    const u16* b0 = Be + (size_t)(n0 + srow) * K + st_k;
    const u16* b1 = Be + (size_t)(n0 + srow + 64) * K + st_k;

    f32x4 acc[4][4];
    #pragma unroll
    for (int i = 0; i < 4; ++i)
        #pragma unroll
        for (int j = 0; j < 4; ++j) acc[i][j] = (f32x4){0.f, 0.f, 0.f, 0.f};

    const int lane = tid & 63;
    const int wv = tid >> 6;
    const int wr = (wv >> 1) * 64;
    const int wc = (wv & 1) * 64;
    const int lrow = lane & 15;
    const int lkb = (lane >> 4) * 8;

    int offA[4], offB[4];
    #pragma unroll
    for (int m = 0; m < 4; ++m) offA[m] = (wr + m * 16 + lrow) * 32 + lkb;
    #pragma unroll
    for (int n = 0; n < 4; ++n) offB[n] = (wc + n * 16 + lrow) * 32 + lkb;

#define STAGE_DN(ps) do { \
    glds16(a0, &As[(ps) + tid * 8]); \
    glds16(a1, &As[(ps) + 2048 + tid * 8]); \
    glds16(b0, &Bs[(ps) + tid * 8]); \
    glds16(b1, &Bs[(ps) + 2048 + tid * 8]); \
    a0 += 32; a1 += 32; b0 += 32; b1 += 32; } while (0)

#define COMPUTE_DN(ps) do { \
    bf16x8 af[4], bff[4]; \
    _Pragma("unroll") for (int m = 0; m < 4; ++m) af[m] = *(const bf16x8*)&As[(ps) + offA[m]]; \
    _Pragma("unroll") for (int n = 0; n < 4; ++n) bff[n] = *(const bf16x8*)&Bs[(ps) + offB[n]]; \
    _Pragma("unroll") for (int m = 0; m < 4; ++m) \
        _Pragma("unroll") for (int n = 0; n < 4; ++n) \
            acc[m][n] = __builtin_amdgcn_mfma_f32_16x16x32_bf16(af[m], bff[n], acc[m][n], 0, 0, 0); \
    } while (0)

    STAGE_DN(0);
    STAGE_DN(4096);
    #pragma unroll 1
    for (int t = 0; t < NT - 2; ++t) {
        asm volatile("s_waitcnt vmcnt(4)" ::: "memory");
        __builtin_amdgcn_s_barrier();
        const int ps = (t & 1) * 4096;
        COMPUTE_DN(ps);
        __builtin_amdgcn_s_barrier();
        STAGE_DN(ps);
    }
    asm volatile("s_waitcnt vmcnt(4)" ::: "memory");
    __builtin_amdgcn_s_barrier();
    COMPUTE_DN(0);            // NT even: (NT-2)&1 == 0
    asm volatile("s_waitcnt vmcnt(0)" ::: "memory");
    __builtin_amdgcn_s_barrier();
    COMPUTE_DN(4096);         // (NT-1)&1 == 1

    const int l4 = (lane >> 4) * 4;
    #pragma unroll
    for (int m = 0; m < 4; ++m)
        #pragma unroll
        for (int n = 0; n < 4; ++n)
            #pragma unroll
            for (int j = 0; j < 4; ++j) {
                int r = wr + m * 16 + l4 + j;
                if (m0 + r < cnt) {
                    int c = n0 + wc + n * 16 + lrow;
                    Outp[(size_t)(base + m0 + r) * HDIM + c] = acc[m][n][j];
                }
            }
}

// ---------------- combine: out = sgate*out + w0*Dexp[s0] + w1*Dexp[s1] ----------------
__global__ __launch_bounds__(256) void combine_kernel(
    const float* __restrict__ Dexp,
    const int* __restrict__ slot, const float* __restrict__ topk_w,
    const float* __restrict__ sgate, float* __restrict__ Out)
{
    int idx = blockIdx.x * 256 + threadIdx.x;
    int t = idx >> 8;
    int c = (idx & 255) * 4;
    int s0 = slot[2 * t], s1 = slot[2 * t + 1];
    float w0 = topk_w[2 * t], w1 = topk_w[2 * t + 1], sg = sgate[t];
    f32x4 sh = *(const f32x4*)(Out + (size_t)t * HDIM + c);
    f32x4 d0 = *(const f32x4*)(Dexp + (size_t)s0 * HDIM + c);
    f32x4 d1 = *(const f32x4*)(Dexp + (size_t)s1 * HDIM + c);
    f32x4 o;
    #pragma unroll
    for (int j = 0; j < 4; ++j) o[j] = sg * sh[j] + w0 * d0[j] + w1 * d1[j];
    *(f32x4*)(Out + (size_t)t * HDIM + c) = o;
}

// ---------------- launch ----------------
extern "C" void kernel_launch(void* const* d_in, const int* in_sizes, int n_in,
                              void* d_out, int out_size, void* d_ws, size_t ws_size,
                              hipStream_t stream)
{
    const float* X   = (const float*)d_in[0];
    const float* GW  = (const float*)d_in[1];
    const float* WG  = (const float*)d_in[2];
    const float* WU  = (const float*)d_in[3];
    const float* WD  = (const float*)d_in[4];
    const float* SG  = (const float*)d_in[5];
    const float* SU  = (const float*)d_in[6];
    const float* SD  = (const float*)d_in[7];
    const float* SEG = (const float*)d_in[8];
    float* Out = (float*)d_out;

    char* ws = (char*)d_ws;
    int*   counts    = (int*)(ws + 0);
    int*   seg_start = (int*)(ws + 64);
    int*   cursors   = (int*)(ws + 128);
    int*   topk_e    = (int*)(ws + 1024);
    float* topk_w    = (float*)(ws + 1024 + 32768);
    float* sgate     = (float*)(ws + 1024 + 65536);
    int*   tok_ids   = (int*)(ws + 1024 + 65536 + 16384);
    int*   slot      = (int*)(ws + 1024 + 65536 + 16384 + 32768);

    u16* Xbf  = (u16*)(ws + 0x40000ull);     // 8.4 MB
    u16* Hact = (u16*)(ws + 0xA00000ull);    // 23.1 MB (slot-major [8192][1408])
    u16* Hs   = (u16*)(ws + 0x2200000ull);   // 23.1 MB ([4096][2816])
    u16* WGUt = (u16*)(ws + 0x3A00000ull);   // 46.1 MB (8x[I][H] gate, then 8x[I][H] up)
    u16* WDt  = (u16*)(ws + 0x6900000ull);   // 23.1 MB (8x[H][I])
    u16* SGUt = (u16*)(ws + 0x8100000ull);   // 11.5 MB ([IS][H] gate, up)
    u16* SDt  = (u16*)(ws + 0x8D00000ull);   // 5.8 MB ([H][IS])
    u16* WGt = WGUt;
    u16* WUt = WGUt + (size_t)NEXP * IDIM * HDIM;
    u16* SGt = SGUt;
    u16* SUt = SGUt + (size_t)ISDIM * HDIM;
    // Dexp aliases WGUt (needs 33.5 MB <= 46.1 MB); written only after gemm_gu done
    float* Dexp = (float*)(ws + 0x3A00000ull);

    hipMemsetAsync(counts, 0, 64, stream);

    // routing
    route_kernel<<<T_TOK / 4, 256, 0, stream>>>(X, GW, SEG, topk_e, topk_w, sgate);
    hist_kernel<<<(T_TOK * 2) / 256, 256, 0, stream>>>(topk_e, counts);
    offsets_kernel<<<1, 64, 0, stream>>>(counts, seg_start, cursors);
    scatter_kernel<<<(T_TOK * 2) / 256, 256, 0, stream>>>(topk_e, cursors, tok_ids, slot);

    // converts
    cvt_x_kernel<<<(T_TOK * HDIM) / (256 * 8), 256, 0, stream>>>(X, Xbf, T_TOK * HDIM);
    transpose_cvt<<<dim3(IDIM / 64, HDIM / 64, 2 * NEXP), 256, 0, stream>>>(WG, WU, WGUt, HDIM, IDIM, NEXP);
    transpose_cvt<<<dim3(HDIM / 64, IDIM / 64, NEXP), 256, 0, stream>>>(WD, WD, WDt, IDIM, HDIM, NEXP);
    transpose_cvt<<<dim3(ISDIM / 64, HDIM / 64, 2), 256, 0, stream>>>(SG, SU, SGUt, HDIM, ISDIM, 1);
    transpose_cvt<<<dim3(HDIM / 64, ISDIM / 64, 1), 256, 0, stream>>>(SD, SD, SDt, ISDIM, HDIM, 1);

    // expert gate+up (XCD-affine: blockIdx.x = expert, n-tile outermost)
    gemm_gu<<<dim3(NEXP, T_TOK / 128, IDIM / 64), 256, 0, stream>>>(
        Xbf, WGt, WUt, (size_t)IDIM * HDIM, Hact,
        tok_ids, seg_start, counts, IDIM, 0);
    // shared gate+up
    gemm_gu<<<dim3(8, T_TOK / 128 / 8, ISDIM / 64), 256, 0, stream>>>(
        Xbf, SGt, SUt, 0, Hs,
        nullptr, nullptr, nullptr, ISDIM, T_TOK);

    // merged down: expert -> Dexp (raw), shared -> Out (raw)
    gemm_down<<<dim3(72, T_TOK / 128), 256, 0, stream>>>(
        Hact, Hs, WDt, SDt, Dexp, Out,
        seg_start, counts);

    // final combine (reads shared value from Out, rewrites Out)
    combine_kernel<<<(T_TOK * HDIM / 4) / 256, 256, 0, stream>>>(
        Dexp, slot, topk_w, sgate, Out);
}

// Round 7
// 342.409 us; speedup vs baseline: 2.1290x; 1.0314x over previous
//
#include <hip/hip_runtime.h>
#include <hip/hip_bf16.h>

#define T_TOK 4096
#define HDIM  1024
#define NEXP  8
#define IDIM  1408
#define ISDIM 2816

typedef short bf16x8 __attribute__((ext_vector_type(8)));
typedef float f32x4  __attribute__((ext_vector_type(4)));
typedef unsigned short u16;
typedef unsigned short u16x4 __attribute__((ext_vector_type(4)));
typedef unsigned short u16x8 __attribute__((ext_vector_type(8)));

typedef __attribute__((address_space(1))) const void gvoid;
typedef __attribute__((address_space(3))) void lvoid;

__device__ __forceinline__ u16 f2bf(float f) {
    union { float f; unsigned u; } c; c.f = f;
    unsigned r = (c.u + 0x7FFFu + ((c.u >> 16) & 1u)) >> 16;
    return (u16)r;
}
__device__ __forceinline__ float bf2f(u16 v) {
    union { unsigned u; float f; } c; c.u = (unsigned)v << 16; return c.f;
}
__device__ __forceinline__ void glds16(const u16* g, u16* l) {
    __builtin_amdgcn_global_load_lds((gvoid*)g, (lvoid*)l, 16, 0, 0);
}

// ---------------- routing: one wave per token (no atomics) ----------------
__global__ __launch_bounds__(256) void route_kernel(
    const float* __restrict__ X, const float* __restrict__ GW,
    const float* __restrict__ SEG,
    int* __restrict__ topk_e, float* __restrict__ topk_w,
    float* __restrict__ sgate)
{
    const int t = blockIdx.x * 4 + (threadIdx.x >> 6);
    const int lane = threadIdx.x & 63;
    float acc[NEXP];
    #pragma unroll
    for (int e = 0; e < NEXP; ++e) acc[e] = 0.f;
    float sacc = 0.f;
    const float* xr = X + (size_t)t * HDIM;
    for (int h = lane; h < HDIM; h += 64) {
        float xv = xr[h];
        f32x4 g0 = *(const f32x4*)(GW + (size_t)h * NEXP);
        f32x4 g1 = *(const f32x4*)(GW + (size_t)h * NEXP + 4);
        acc[0] += xv * g0[0]; acc[1] += xv * g0[1];
        acc[2] += xv * g0[2]; acc[3] += xv * g0[3];
        acc[4] += xv * g1[0]; acc[5] += xv * g1[1];
        acc[6] += xv * g1[2]; acc[7] += xv * g1[3];
        sacc += xv * SEG[h];
    }
    #pragma unroll
    for (int off = 32; off > 0; off >>= 1) {
        #pragma unroll
        for (int e = 0; e < NEXP; ++e) acc[e] += __shfl_down(acc[e], off);
        sacc += __shfl_down(sacc, off);
    }
    if (lane == 0) {
        int e0 = 0;
        #pragma unroll
        for (int e = 1; e < NEXP; ++e) if (acc[e] > acc[e0]) e0 = e;
        int e1 = (e0 == 0) ? 1 : 0;
        #pragma unroll
        for (int e = 0; e < NEXP; ++e)
            if (e != e0 && acc[e] > acc[e1]) e1 = e;
        float w0 = 1.f / (1.f + __expf(acc[e1] - acc[e0]));
        topk_e[t * 2]     = e0; topk_e[t * 2 + 1] = e1;
        topk_w[t * 2]     = w0; topk_w[t * 2 + 1] = 1.f - w0;
        sgate[t] = 1.f / (1.f + __expf(-sacc));
    }
}

// ---------------- histogram: LDS-aggregated ----------------
__global__ __launch_bounds__(256) void hist_kernel(
    const int* __restrict__ topk_e, int* __restrict__ counts)
{
    __shared__ int h[NEXP];
    if (threadIdx.x < NEXP) h[threadIdx.x] = 0;
    __syncthreads();
    int i = blockIdx.x * 256 + threadIdx.x;
    atomicAdd(&h[topk_e[i]], 1);
    __syncthreads();
    if (threadIdx.x < NEXP) atomicAdd(&counts[threadIdx.x], h[threadIdx.x]);
}

__global__ void offsets_kernel(const int* __restrict__ counts,
                               int* __restrict__ seg_start,
                               int* __restrict__ cursors)
{
    if (threadIdx.x == 0) {
        int s = 0;
        for (int e = 0; e < NEXP; ++e) {
            seg_start[e] = s; cursors[e] = s; s += counts[e];
        }
    }
}

// ---------------- scatter: wave-ballot aggregated atomics + slot inverse map ----------------
__global__ __launch_bounds__(256) void scatter_kernel(
    const int* __restrict__ topk_e,
    int* __restrict__ cursors, int* __restrict__ tok_ids,
    int* __restrict__ slot)
{
    const int i = blockIdx.x * 256 + threadIdx.x;
    const int lane = threadIdx.x & 63;
    const int e = topk_e[i];
    const unsigned long long lt = (1ull << lane) - 1ull;
    #pragma unroll
    for (int ex = 0; ex < NEXP; ++ex) {
        unsigned long long mask = __ballot(e == ex);
        if (mask == 0ull) continue;
        int cnt = __popcll(mask);
        int leader = __ffsll((long long)mask) - 1;
        int base_ = 0;
        if (lane == leader) base_ = atomicAdd(&cursors[ex], cnt);
        base_ = __shfl(base_, leader);
        if (e == ex) {
            int pos = base_ + __popcll(mask & lt);
            tok_ids[pos] = i >> 1;
            slot[i] = pos;
        }
    }
}

// ---------------- converts ----------------
__global__ __launch_bounds__(256) void cvt_x_kernel(
    const float* __restrict__ in, u16* __restrict__ out, int n)
{
    int i = (blockIdx.x * 256 + threadIdx.x) * 8;
    if (i < n) {
        f32x4 a = *(const f32x4*)(in + i);
        f32x4 b = *(const f32x4*)(in + i + 4);
        u16x8 o;
        #pragma unroll
        for (int j = 0; j < 4; ++j) { o[j] = f2bf(a[j]); o[j + 4] = f2bf(b[j]); }
        *(u16x8*)(out + i) = o;
    }
}

// in fp32 [K][N] (z-th slice from in0 if z<split else in1), out bf16 [N][K]
__global__ __launch_bounds__(256) void transpose_cvt(
    const float* __restrict__ in0, const float* __restrict__ in1,
    u16* __restrict__ out, int K, int N, int split)
{
    const int z = blockIdx.z;
    const float* in = (z < split) ? (in0 + (size_t)z * K * N)
                                  : (in1 + (size_t)(z - split) * K * N);
    u16* o = out + (size_t)z * N * K;

    __shared__ float tile[64][65];
    const int n0 = blockIdx.x * 64, k0 = blockIdx.y * 64;
    const int tx = threadIdx.x & 15;
    const int ty = threadIdx.x >> 4;

    #pragma unroll
    for (int p = 0; p < 4; ++p) {
        int k = ty + p * 16;
        f32x4 v = *(const f32x4*)(in + (size_t)(k0 + k) * N + n0 + tx * 4);
        *(f32x4*)&tile[k][tx * 4] = v;
    }
    __syncthreads();
    #pragma unroll
    for (int p = 0; p < 4; ++p) {
        int n = ty + p * 16;
        u16x4 w;
        #pragma unroll
        for (int j = 0; j < 4; ++j) w[j] = f2bf(tile[tx * 4 + j][n]);
        *(u16x4*)(o + (size_t)(n0 + n) * K + k0 + tx * 4) = w;
    }
}

// ---------------- fused gate+up GEMM: 128M x 64N, counted-vmcnt dbuf, silu epilogue ----------------
// expert mode (counts!=null): grid(8, 32, 22): e=bx, m=by, n=bz
// shared mode (counts==null): grid(8, 4, 44): m = bx*4+by, n=bz
__global__ __launch_bounds__(256) void gemm_gu(
    const u16* __restrict__ A,
    const u16* __restrict__ Bg_, const u16* __restrict__ Bu_, size_t b_stride,
    u16* __restrict__ Hout,
    const int* __restrict__ a_ids, const int* __restrict__ seg_start,
    const int* __restrict__ counts,
    int N, int Trows)
{
    int e, m_tile, cnt, base;
    if (counts) {
        e = blockIdx.x; m_tile = blockIdx.y;
        cnt = counts[e]; base = seg_start[e];
    } else {
        e = 0; m_tile = blockIdx.x * gridDim.y + blockIdx.y;
        cnt = Trows; base = 0;
    }
    const int m0 = m_tile * 128;
    if (m0 >= cnt) return;
    const int n0 = blockIdx.z * 64;
    const u16* Bg = Bg_ + (size_t)e * b_stride;
    const u16* Bu = Bu_ + (size_t)e * b_stride;
    const int K = HDIM;   // 1024 -> NT = 32

    __shared__ u16 As[2 * 4096];   // [buf][row 0..127][k 0..31]
    __shared__ u16 Bs[2 * 4096];   // [buf][rows 0..63 gate | 64..127 up][k]

    const int tid = threadIdx.x;
    const int srow = tid >> 2;
    const int st_k = (tid & 3) * 8;
    int ar0 = m0 + srow;       if (ar0 >= cnt) ar0 = cnt - 1;
    int ar1 = m0 + srow + 64;  if (ar1 >= cnt) ar1 = cnt - 1;
    const int ga0 = a_ids ? a_ids[base + ar0] : (base + ar0);
    const int ga1 = a_ids ? a_ids[base + ar1] : (base + ar1);
    const u16* a0 = A + (size_t)ga0 * K + st_k;
    const u16* a1 = A + (size_t)ga1 * K + st_k;
    const u16* bg = Bg + (size_t)(n0 + srow) * K + st_k;
    const u16* bu = Bu + (size_t)(n0 + srow) * K + st_k;

    f32x4 accG[4][2], accU[4][2];
    #pragma unroll
    for (int i = 0; i < 4; ++i)
        #pragma unroll
        for (int j = 0; j < 2; ++j) {
            accG[i][j] = (f32x4){0.f, 0.f, 0.f, 0.f};
            accU[i][j] = (f32x4){0.f, 0.f, 0.f, 0.f};
        }

    const int lane = tid & 63;
    const int wv = tid >> 6;
    const int wr = (wv >> 1) * 64;
    const int wc = (wv & 1) * 32;
    const int lrow = lane & 15;
    const int lkb = (lane >> 4) * 8;

    int offA[4], offBg[2];
    #pragma unroll
    for (int m = 0; m < 4; ++m) offA[m] = (wr + m * 16 + lrow) * 32 + lkb;
    #pragma unroll
    for (int n = 0; n < 2; ++n) offBg[n] = (wc + n * 16 + lrow) * 32 + lkb;

#define STAGE_GU(ps) do { \
    glds16(a0, &As[(ps) + tid * 8]); \
    glds16(a1, &As[(ps) + 2048 + tid * 8]); \
    glds16(bg, &Bs[(ps) + tid * 8]); \
    glds16(bu, &Bs[(ps) + 2048 + tid * 8]); \
    a0 += 32; a1 += 32; bg += 32; bu += 32; } while (0)

#define COMPUTE_GU(ps) do { \
    bf16x8 af[4], bgf[2], bux[2]; \
    _Pragma("unroll") for (int m = 0; m < 4; ++m) af[m] = *(const bf16x8*)&As[(ps) + offA[m]]; \
    _Pragma("unroll") for (int n = 0; n < 2; ++n) { \
        bgf[n] = *(const bf16x8*)&Bs[(ps) + offBg[n]]; \
        bux[n] = *(const bf16x8*)&Bs[(ps) + offBg[n] + 2048]; } \
    _Pragma("unroll") for (int m = 0; m < 4; ++m) \
        _Pragma("unroll") for (int n = 0; n < 2; ++n) { \
            accG[m][n] = __builtin_amdgcn_mfma_f32_16x16x32_bf16(af[m], bgf[n], accG[m][n], 0, 0, 0); \
            accU[m][n] = __builtin_amdgcn_mfma_f32_16x16x32_bf16(af[m], bux[n], accU[m][n], 0, 0, 0); } \
    } while (0)

    STAGE_GU(0);
    STAGE_GU(4096);
    #pragma unroll 1
    for (int t = 0; t < 30; ++t) {
        asm volatile("s_waitcnt vmcnt(4)" ::: "memory");
        __builtin_amdgcn_s_barrier();
        const int ps = (t & 1) * 4096;
        COMPUTE_GU(ps);
        __builtin_amdgcn_s_barrier();
        STAGE_GU(ps);
    }
    asm volatile("s_waitcnt vmcnt(4)" ::: "memory");
    __builtin_amdgcn_s_barrier();
    COMPUTE_GU(0);
    asm volatile("s_waitcnt vmcnt(0)" ::: "memory");
    __builtin_amdgcn_s_barrier();
    COMPUTE_GU(4096);

    const int l4 = (lane >> 4) * 4;
    #pragma unroll
    for (int m = 0; m < 4; ++m)
        #pragma unroll
        for (int n = 0; n < 2; ++n)
            #pragma unroll
            for (int j = 0; j < 4; ++j) {
                int r = wr + m * 16 + l4 + j;
                if (m0 + r < cnt) {
                    int c = n0 + wc + n * 16 + lrow;
                    float g = accG[m][n][j], u = accU[m][n][j];
                    float hv = g / (1.f + __expf(-g)) * u;
                    Hout[(size_t)(base + m0 + r) * N + c] = f2bf(hv);
                }
            }
}

// ---------------- down GEMM: 128x128, counted-vmcnt dbuf, balanced NT=44 ----------------
// zz < 64: expert (e = zz&7, n-tile = zz>>3, K=IDIM, A=Hact) -> store Dexp
// zz in [64,80): shared k-chunk (idx=zz-64: n-tile = idx&7, kc = idx>>3),
//                K-chunk of 1408 from ISDIM -> atomicAdd into Out. grid(80, 32).
__global__ __launch_bounds__(256) void gemm_down(
    const u16* __restrict__ AE, const u16* __restrict__ AS,
    const u16* __restrict__ WDt, const u16* __restrict__ SDt,
    float* __restrict__ DexpO, float* __restrict__ OutS,
    const int* __restrict__ seg_start, const int* __restrict__ counts)
{
    const int zz = blockIdx.x;
    const bool shr = (zz >= 64);
    int n0, cnt, base, kstride;
    size_t koff;
    const u16 *Ab, *Be;
    if (!shr) {
        int e = zz & 7;
        n0 = (zz >> 3) * 128;
        cnt = counts[e]; base = seg_start[e];
        Ab = AE; Be = WDt + (size_t)e * (HDIM * IDIM);
        kstride = IDIM; koff = 0;
    } else {
        int idx = zz - 64;
        n0 = (idx & 7) * 128;
        cnt = T_TOK; base = 0;
        Ab = AS; Be = SDt;
        kstride = ISDIM; koff = (size_t)(idx >> 3) * 1408;
    }
    const int m0 = blockIdx.y * 128;
    if (m0 >= cnt) return;
    const int NT = 44;   // 1408 / 32 for both paths

    __shared__ u16 As[2 * 4096];
    __shared__ u16 Bs[2 * 4096];

    const int tid = threadIdx.x;
    const int srow = tid >> 2;
    const int st_k = (tid & 3) * 8;
    int ar0 = m0 + srow;       if (ar0 >= cnt) ar0 = cnt - 1;
    int ar1 = m0 + srow + 64;  if (ar1 >= cnt) ar1 = cnt - 1;
    const u16* a0 = Ab + (size_t)(base + ar0) * kstride + koff + st_k;
    const u16* a1 = Ab + (size_t)(base + ar1) * kstride + koff + st_k;
    const u16* b0 = Be + (size_t)(n0 + srow) * kstride + koff + st_k;
    const u16* b1 = Be + (size_t)(n0 + srow + 64) * kstride + koff + st_k;

    f32x4 acc[4][4];
    #pragma unroll
    for (int i = 0; i < 4; ++i)
        #pragma unroll
        for (int j = 0; j < 4; ++j) acc[i][j] = (f32x4){0.f, 0.f, 0.f, 0.f};

    const int lane = tid & 63;
    const int wv = tid >> 6;
    const int wr = (wv >> 1) * 64;
    const int wc = (wv & 1) * 64;
    const int lrow = lane & 15;
    const int lkb = (lane >> 4) * 8;

    int offA[4], offB[4];
    #pragma unroll
    for (int m = 0; m < 4; ++m) offA[m] = (wr + m * 16 + lrow) * 32 + lkb;
    #pragma unroll
    for (int n = 0; n < 4; ++n) offB[n] = (wc + n * 16 + lrow) * 32 + lkb;

#define STAGE_DN(ps) do { \
    glds16(a0, &As[(ps) + tid * 8]); \
    glds16(a1, &As[(ps) + 2048 + tid * 8]); \
    glds16(b0, &Bs[(ps) + tid * 8]); \
    glds16(b1, &Bs[(ps) + 2048 + tid * 8]); \
    a0 += 32; a1 += 32; b0 += 32; b1 += 32; } while (0)

#define COMPUTE_DN(ps) do { \
    bf16x8 af[4], bff[4]; \
    _Pragma("unroll") for (int m = 0; m < 4; ++m) af[m] = *(const bf16x8*)&As[(ps) + offA[m]]; \
    _Pragma("unroll") for (int n = 0; n < 4; ++n) bff[n] = *(const bf16x8*)&Bs[(ps) + offB[n]]; \
    _Pragma("unroll") for (int m = 0; m < 4; ++m) \
        _Pragma("unroll") for (int n = 0; n < 4; ++n) \
            acc[m][n] = __builtin_amdgcn_mfma_f32_16x16x32_bf16(af[m], bff[n], acc[m][n], 0, 0, 0); \
    } while (0)

    STAGE_DN(0);
    STAGE_DN(4096);
    #pragma unroll 1
    for (int t = 0; t < NT - 2; ++t) {
        asm volatile("s_waitcnt vmcnt(4)" ::: "memory");
        __builtin_amdgcn_s_barrier();
        const int ps = (t & 1) * 4096;
        COMPUTE_DN(ps);
        __builtin_amdgcn_s_barrier();
        STAGE_DN(ps);
    }
    asm volatile("s_waitcnt vmcnt(4)" ::: "memory");
    __builtin_amdgcn_s_barrier();
    COMPUTE_DN(0);            // NT even: (NT-2)&1 == 0
    asm volatile("s_waitcnt vmcnt(0)" ::: "memory");
    __builtin_amdgcn_s_barrier();
    COMPUTE_DN(4096);         // (NT-1)&1 == 1

    const int l4 = (lane >> 4) * 4;
    #pragma unroll
    for (int m = 0; m < 4; ++m)
        #pragma unroll
        for (int n = 0; n < 4; ++n)
            #pragma unroll
            for (int j = 0; j < 4; ++j) {
                int r = wr + m * 16 + l4 + j;
                if (m0 + r < cnt) {
                    int c = n0 + wc + n * 16 + lrow;
                    if (!shr)
                        DexpO[(size_t)(base + m0 + r) * HDIM + c] = acc[m][n][j];
                    else
                        atomicAdd(&OutS[(size_t)(m0 + r) * HDIM + c], acc[m][n][j]);
                }
            }
}

// ---------------- combine: out = sgate*out + w0*Dexp[s0] + w1*Dexp[s1] ----------------
__global__ __launch_bounds__(256) void combine_kernel(
    const float* __restrict__ Dexp,
    const int* __restrict__ slot, const float* __restrict__ topk_w,
    const float* __restrict__ sgate, float* __restrict__ Out)
{
    int idx = blockIdx.x * 256 + threadIdx.x;
    int t = idx >> 8;
    int c = (idx & 255) * 4;
    int s0 = slot[2 * t], s1 = slot[2 * t + 1];
    float w0 = topk_w[2 * t], w1 = topk_w[2 * t + 1], sg = sgate[t];
    f32x4 sh = *(const f32x4*)(Out + (size_t)t * HDIM + c);
    f32x4 d0 = *(const f32x4*)(Dexp + (size_t)s0 * HDIM + c);
    f32x4 d1 = *(const f32x4*)(Dexp + (size_t)s1 * HDIM + c);
    f32x4 o;
    #pragma unroll
    for (int j = 0; j < 4; ++j) o[j] = sg * sh[j] + w0 * d0[j] + w1 * d1[j];
    *(f32x4*)(Out + (size_t)t * HDIM + c) = o;
}

// ---------------- launch ----------------
extern "C" void kernel_launch(void* const* d_in, const int* in_sizes, int n_in,
                              void* d_out, int out_size, void* d_ws, size_t ws_size,
                              hipStream_t stream)
{
    const float* X   = (const float*)d_in[0];
    const float* GW  = (const float*)d_in[1];
    const float* WG  = (const float*)d_in[2];
    const float* WU  = (const float*)d_in[3];
    const float* WD  = (const float*)d_in[4];
    const float* SG  = (const float*)d_in[5];
    const float* SU  = (const float*)d_in[6];
    const float* SD  = (const float*)d_in[7];
    const float* SEG = (const float*)d_in[8];
    float* Out = (float*)d_out;

    char* ws = (char*)d_ws;
    int*   counts    = (int*)(ws + 0);
    int*   seg_start = (int*)(ws + 64);
    int*   cursors   = (int*)(ws + 128);
    int*   topk_e    = (int*)(ws + 1024);
    float* topk_w    = (float*)(ws + 1024 + 32768);
    float* sgate     = (float*)(ws + 1024 + 65536);
    int*   tok_ids   = (int*)(ws + 1024 + 65536 + 16384);
    int*   slot      = (int*)(ws + 1024 + 65536 + 16384 + 32768);

    u16* Xbf  = (u16*)(ws + 0x40000ull);     // 8.4 MB
    u16* Hact = (u16*)(ws + 0xA00000ull);    // 23.1 MB (slot-major [8192][1408])
    u16* Hs   = (u16*)(ws + 0x2200000ull);   // 23.1 MB ([4096][2816])
    u16* WGUt = (u16*)(ws + 0x3A00000ull);   // 46.1 MB (8x[I][H] gate, then 8x[I][H] up)
    u16* WDt  = (u16*)(ws + 0x6900000ull);   // 23.1 MB (8x[H][I])
    u16* SGUt = (u16*)(ws + 0x8100000ull);   // 11.5 MB ([IS][H] gate, up)
    u16* SDt  = (u16*)(ws + 0x8D00000ull);   // 5.8 MB ([H][IS])
    u16* WGt = WGUt;
    u16* WUt = WGUt + (size_t)NEXP * IDIM * HDIM;
    u16* SGt = SGUt;
    u16* SUt = SGUt + (size_t)ISDIM * HDIM;
    // Dexp aliases WGUt (needs 33.5 MB <= 46.1 MB); written only after gemm_gu done
    float* Dexp = (float*)(ws + 0x3A00000ull);

    hipMemsetAsync(counts, 0, 64, stream);
    hipMemsetAsync(Out, 0, (size_t)T_TOK * HDIM * sizeof(float), stream);

    // routing
    route_kernel<<<T_TOK / 4, 256, 0, stream>>>(X, GW, SEG, topk_e, topk_w, sgate);
    hist_kernel<<<(T_TOK * 2) / 256, 256, 0, stream>>>(topk_e, counts);
    offsets_kernel<<<1, 64, 0, stream>>>(counts, seg_start, cursors);
    scatter_kernel<<<(T_TOK * 2) / 256, 256, 0, stream>>>(topk_e, cursors, tok_ids, slot);

    // converts
    cvt_x_kernel<<<(T_TOK * HDIM) / (256 * 8), 256, 0, stream>>>(X, Xbf, T_TOK * HDIM);
    transpose_cvt<<<dim3(IDIM / 64, HDIM / 64, 2 * NEXP), 256, 0, stream>>>(WG, WU, WGUt, HDIM, IDIM, NEXP);
    transpose_cvt<<<dim3(HDIM / 64, IDIM / 64, NEXP), 256, 0, stream>>>(WD, WD, WDt, IDIM, HDIM, NEXP);
    transpose_cvt<<<dim3(ISDIM / 64, HDIM / 64, 2), 256, 0, stream>>>(SG, SU, SGUt, HDIM, ISDIM, 1);
    transpose_cvt<<<dim3(HDIM / 64, ISDIM / 64, 1), 256, 0, stream>>>(SD, SD, SDt, ISDIM, HDIM, 1);

    // expert gate+up (XCD-affine: blockIdx.x = expert, n-tile outermost)
    gemm_gu<<<dim3(NEXP, T_TOK / 128, IDIM / 64), 256, 0, stream>>>(
        Xbf, WGt, WUt, (size_t)IDIM * HDIM, Hact,
        tok_ids, seg_start, counts, IDIM, 0);
    // shared gate+up
    gemm_gu<<<dim3(8, T_TOK / 128 / 8, ISDIM / 64), 256, 0, stream>>>(
        Xbf, SGt, SUt, 0, Hs,
        nullptr, nullptr, nullptr, ISDIM, T_TOK);

    // merged balanced down: expert -> Dexp (store), shared k-chunks -> Out (atomicAdd)
    gemm_down<<<dim3(80, T_TOK / 128), 256, 0, stream>>>(
        Hact, Hs, WDt, SDt, Dexp, Out,
        seg_start, counts);

    // final combine (reads shared sum from Out, rewrites Out)
    combine_kernel<<<(T_TOK * HDIM / 4) / 256, 256, 0, stream>>>(
        Dexp, slot, topk_w, sgate, Out);
}